// Round 7
// baseline (876.772 us; speedup 1.0000x reference)
//
#include <hip/hip_runtime.h>
#include <cstdint>
#include <cstdio>

typedef __bf16 bf16x8 __attribute__((ext_vector_type(8)));
typedef float  f32x4  __attribute__((ext_vector_type(4)));
typedef const __attribute__((address_space(1))) void* gas_ptr;
typedef __attribute__((address_space(3))) void* las_ptr;

__device__ __forceinline__ uint16_t f32_to_bf16_rne(float f){
  uint32_t u = __builtin_bit_cast(uint32_t, f);
  u += 0x7FFFu + ((u >> 16) & 1u);
  return (uint16_t)(u >> 16);
}
__device__ __forceinline__ float bf16_to_f32(uint16_t h){
  uint32_t u = (uint32_t)h << 16;
  return __builtin_bit_cast(float, u);
}
__device__ __forceinline__ float gelu_exact(float x){
  return 0.5f * x * (1.f + erff(x * 0.7071067811865475f));
}

// ---------------------------------------------------------------------------
// GEMM: C[M,N] = A[M,K](bf16) * Bt[N,K](bf16)^T + bias, epilogue variants.
// EPI 0: Cf[idx] = v + auxF[idx]                       (f32 out, f32 residual)
// EPI 1: col<SPLIT: Cb0 = bf16(gelu(v)) ; else Cb1 = bf16(v)   (split halves)
// EPI 2: Cb0[row*N+col] = bf16(v)                      (raw bf16, merged buf)
// EPI 3: Cb0[row*N+col] = bf16(v * bf16(auxB[idx]))    (gated mul)
// 128x128 tile, BK=32, 4 waves, global_load_lds(16B), XOR swizzle on k-chunks.
// __launch_bounds__(256,3): force <=~106 VGPR so VGPR+64 AGPR fits 3 waves/EU
// (3 blocks/CU residency -- round-4 measured 2 blocks/CU at 108 VGPR, the
//  occupancy cliff costing ~1.5x vs the m97 reference).
// ---------------------------------------------------------------------------
template<int EPI>
__global__ __launch_bounds__(256, 3)
void gemm_kernel(const uint16_t* __restrict__ A, const uint16_t* __restrict__ Bt,
                 const float* __restrict__ bias0, const float* __restrict__ bias1,
                 const float* __restrict__ auxF, const uint16_t* __restrict__ auxB,
                 float* __restrict__ Cf, uint16_t* __restrict__ Cb0, uint16_t* __restrict__ Cb1,
                 int M, int N, int K, int SPLIT)
{
  __shared__ alignas(16) uint16_t lA[128*32];
  __shared__ alignas(16) uint16_t lB[128*32];
  const int tid  = threadIdx.x;
  const int wid  = tid >> 6;
  const int lane = tid & 63;
  const int n0 = blockIdx.x * 128;
  const int m0 = blockIdx.y * 128;
  const int wr = wid >> 1, wc = wid & 1;

  // staging: slot s holds 16B at lds byte s*16 = row*64 + cp*16 (tile [128][32] bf16)
  // slot (row,cp) gets global k-chunk c = cp ^ ((row>>1)&3)  (2-way-free swizzle)
  const int s0 = tid, s1 = 256 + tid;
  const int r0 = s0 >> 2, c0 = (s0 & 3) ^ ((r0 >> 1) & 3);
  const int r1 = s1 >> 2, c1 = (s1 & 3) ^ ((r1 >> 1) & 3);
  const uint16_t* gA0 = A  + (size_t)(m0 + r0) * K + c0 * 8;
  const uint16_t* gA1 = A  + (size_t)(m0 + r1) * K + c1 * 8;
  const uint16_t* gB0 = Bt + (size_t)(n0 + r0) * K + c0 * 8;
  const uint16_t* gB1 = Bt + (size_t)(n0 + r1) * K + c1 * 8;
  uint16_t* lA0 = &lA[(wid * 64) * 8];
  uint16_t* lA1 = &lA[(256 + wid * 64) * 8];
  uint16_t* lB0 = &lB[(wid * 64) * 8];
  uint16_t* lB1 = &lB[(256 + wid * 64) * 8];

  f32x4 acc[4][4];
  const f32x4 fzero = {0.f, 0.f, 0.f, 0.f};
#pragma unroll
  for (int m = 0; m < 4; m++)
#pragma unroll
    for (int n = 0; n < 4; n++) acc[m][n] = fzero;

  const int la = lane & 15, lb = lane >> 4;
  int offA[4], offB[4];
#pragma unroll
  for (int m = 0; m < 4; m++){
    int row = wr*64 + m*16 + la;
    offA[m] = row*64 + ((lb ^ ((row >> 1) & 3)) << 4);
  }
#pragma unroll
  for (int n = 0; n < 4; n++){
    int row = wc*64 + n*16 + la;
    offB[n] = row*64 + ((lb ^ ((row >> 1) & 3)) << 4);
  }
  const char* lAc = (const char*)lA;
  const char* lBc = (const char*)lB;

  for (int ks = 0; ks < K; ks += 32){
    __syncthreads();
    __builtin_amdgcn_global_load_lds((gas_ptr)(gA0 + ks), (las_ptr)lA0, 16, 0, 0);
    __builtin_amdgcn_global_load_lds((gas_ptr)(gA1 + ks), (las_ptr)lA1, 16, 0, 0);
    __builtin_amdgcn_global_load_lds((gas_ptr)(gB0 + ks), (las_ptr)lB0, 16, 0, 0);
    __builtin_amdgcn_global_load_lds((gas_ptr)(gB1 + ks), (las_ptr)lB1, 16, 0, 0);
    __syncthreads();
    bf16x8 af[4], bfr[4];
#pragma unroll
    for (int m = 0; m < 4; m++) af[m]  = *(const bf16x8*)(lAc + offA[m]);
#pragma unroll
    for (int n = 0; n < 4; n++) bfr[n] = *(const bf16x8*)(lBc + offB[n]);
#pragma unroll
    for (int m = 0; m < 4; m++)
#pragma unroll
      for (int n = 0; n < 4; n++)
        acc[m][n] = __builtin_amdgcn_mfma_f32_16x16x32_bf16(af[m], bfr[n], acc[m][n], 0, 0, 0);
  }

  // epilogue: row = m0+wr*64+m*16+(lane>>4)*4+r, col = n0+wc*64+n*16+(lane&15)
#pragma unroll
  for (int n = 0; n < 4; n++){
    int col = n0 + wc*64 + n*16 + la;
    const bool second = (col >= SPLIT);
    float bv = second ? bias1[col - SPLIT] : bias0[col];
#pragma unroll
    for (int m = 0; m < 4; m++){
      int rbase = m0 + wr*64 + m*16 + lb*4;
#pragma unroll
      for (int r = 0; r < 4; r++){
        int row = rbase + r;
        size_t idx = (size_t)row * N + col;
        float v = acc[m][n][r] + bv;
        if constexpr (EPI == 0) Cf[idx] = v + auxF[idx];
        if constexpr (EPI == 1) {
          if (!second) Cb0[(size_t)row * SPLIT + col] = f32_to_bf16_rne(gelu_exact(v));
          else         Cb1[(size_t)row * (N - SPLIT) + (col - SPLIT)] = f32_to_bf16_rne(v);
        }
        if constexpr (EPI == 2) Cb0[idx] = f32_to_bf16_rne(v);
        if constexpr (EPI == 3) Cb0[idx] = f32_to_bf16_rne(v * bf16_to_f32(auxB[idx]));
      }
    }
  }
}

// ---------------------------------------------------------------------------
// Convert + transpose: in[R][C] f32 -> out[C][R] bf16. 64x64 tiles.
// ---------------------------------------------------------------------------
__global__ __launch_bounds__(256)
void cvt_transpose(const float* __restrict__ in, uint16_t* __restrict__ out, int R, int C)
{
  __shared__ float tile[64][65];
  const int r0 = blockIdx.y * 64, c0 = blockIdx.x * 64;
  const int t = threadIdx.x;
  const int lc = (t & 15) * 4;
  const int lr0 = t >> 4;
#pragma unroll
  for (int j = 0; j < 4; j++){
    int lr = lr0 + j*16;
    float4 v = *(const float4*)(in + (size_t)(r0 + lr) * C + c0 + lc);
    tile[lr][lc+0] = v.x; tile[lr][lc+1] = v.y; tile[lr][lc+2] = v.z; tile[lr][lc+3] = v.w;
  }
  __syncthreads();
  const int oc = t >> 2;
  const int rseg = (t & 3) * 16;
  alignas(16) uint16_t tmp[16];
#pragma unroll
  for (int j = 0; j < 16; j++) tmp[j] = f32_to_bf16_rne(tile[rseg + j][oc]);
  uint4* dst = (uint4*)(out + (size_t)(c0 + oc) * R + r0 + rseg);
  dst[0] = *(const uint4*)(&tmp[0]);
  dst[1] = *(const uint4*)(&tmp[8]);
}

// ---------------------------------------------------------------------------
// RMSNorm: per row of D f32 -> bf16. grid = rows, block = 256 (8 elems/thread).
// ---------------------------------------------------------------------------
__global__ __launch_bounds__(256)
void rmsnorm_kernel(const float* __restrict__ x, const float* __restrict__ w,
                    uint16_t* __restrict__ out, int D)
{
  const int row = blockIdx.x;
  const float* xr = x + (size_t)row * D;
  const int base = threadIdx.x * 8;
  float4 va = *(const float4*)(xr + base);
  float4 vb = *(const float4*)(xr + base + 4);
  float ss = va.x*va.x + va.y*va.y + va.z*va.z + va.w*va.w
           + vb.x*vb.x + vb.y*vb.y + vb.z*vb.z + vb.w*vb.w;
#pragma unroll
  for (int o = 32; o > 0; o >>= 1) ss += __shfl_xor(ss, o);
  __shared__ float red[4];
  if ((threadIdx.x & 63) == 0) red[threadIdx.x >> 6] = ss;
  __syncthreads();
  float tot = red[0] + red[1] + red[2] + red[3];
  float inv = rsqrtf(tot / (float)D + 1e-8f);
  float4 wa = *(const float4*)(w + base);
  float4 wb = *(const float4*)(w + base + 4);
  alignas(16) uint16_t tmp[8];
  tmp[0] = f32_to_bf16_rne(va.x * wa.x * inv);
  tmp[1] = f32_to_bf16_rne(va.y * wa.y * inv);
  tmp[2] = f32_to_bf16_rne(va.z * wa.z * inv);
  tmp[3] = f32_to_bf16_rne(va.w * wa.w * inv);
  tmp[4] = f32_to_bf16_rne(vb.x * wb.x * inv);
  tmp[5] = f32_to_bf16_rne(vb.y * wb.y * inv);
  tmp[6] = f32_to_bf16_rne(vb.z * wb.z * inv);
  tmp[7] = f32_to_bf16_rne(vb.w * wb.w * inv);
  *(uint4*)(out + (size_t)row * D + base) = *(const uint4*)tmp;
}

// ---------------------------------------------------------------------------
// Depthwise causal conv K=4 along t, bf16 in/out. grid (H/256, S/128, B)
// ---------------------------------------------------------------------------
__global__ __launch_bounds__(256)
void conv_kernel(const uint16_t* __restrict__ xin, const float* __restrict__ cw,
                 const float* __restrict__ cb, uint16_t* __restrict__ yout,
                 int S, int H)
{
  const int h = blockIdx.x * 256 + threadIdx.x;
  const int b = blockIdx.z;
  const int t0 = blockIdx.y * 128;
  const float w0 = cw[h], w1 = cw[H + h], w2 = cw[2*H + h], w3 = cw[3*H + h];
  const float bias = cb[h];
  const size_t colbase = (size_t)b * S * H + h;
  float xm3 = (t0 >= 3) ? bf16_to_f32(xin[colbase + (size_t)(t0-3)*H]) : 0.f;
  float xm2 = (t0 >= 2) ? bf16_to_f32(xin[colbase + (size_t)(t0-2)*H]) : 0.f;
  float xm1 = (t0 >= 1) ? bf16_to_f32(xin[colbase + (size_t)(t0-1)*H]) : 0.f;
  for (int t = t0; t < t0 + 128; ++t){
    size_t idx = colbase + (size_t)t * H;
    float xt = bf16_to_f32(xin[idx]);
    float y = w0*xm3 + w1*xm2 + w2*xm1 + w3*xt + bias;
    yout[idx] = f32_to_bf16_rne(y);
    xm3 = xm2; xm2 = xm1; xm1 = xt;
  }
}

// ---------------------------------------------------------------------------
// RG-LRU chunked scan over bf16 inputs. gpre[M][2H]: col h = r-preact,
// col H+h = i-preact. convb[M][H] = conv output (the x of the LRU).
// ---------------------------------------------------------------------------
__device__ __forceinline__ void rglru_ab(float rp, float ip, float xc, float coef,
                                         float& a, float& bb)
{
  float r  = 1.f / (1.f + expf(-rp));
  float la = coef * r;
  a = expf(la);
  float mult = sqrtf(-expm1f(2.f * la));
  float ig = 1.f / (1.f + expf(-ip));
  bb = mult * ig * xc;
}

__global__ __launch_bounds__(256)
void scan_phase1(const uint16_t* __restrict__ gpre, const uint16_t* __restrict__ convb,
                 const float* __restrict__ ap,
                 float* __restrict__ SA, float* __restrict__ SB,
                 int S, int H, int T0, int NC)
{
  const int h = blockIdx.x * 256 + threadIdx.x;
  const int j = blockIdx.y, b = blockIdx.z;
  const float coef = -8.f * log1pf(expf(ap[h]));
  size_t rowb = (size_t)b * S + (size_t)j * T0;
  float A = 1.f, Bc = 0.f;
  for (int t = 0; t < T0; ++t){
    size_t row = rowb + t;
    float rp = bf16_to_f32(gpre[row * 2 * H + h]);
    float ip = bf16_to_f32(gpre[row * 2 * H + H + h]);
    float xc = bf16_to_f32(convb[row * H + h]);
    float a, bb; rglru_ab(rp, ip, xc, coef, a, bb);
    A *= a; Bc = a * Bc + bb;
  }
  size_t o = ((size_t)b * NC + j) * H + h;
  SA[o] = A; SB[o] = Bc;
}

__global__ __launch_bounds__(256)
void scan_phase2(const float* __restrict__ SA, const float* __restrict__ SB,
                 float* __restrict__ SH, int H, int NC)
{
  const int h = blockIdx.x * 256 + threadIdx.x;
  const int b = blockIdx.y;
  float hh = 0.f;
  for (int j = 0; j < NC; ++j){
    size_t o = ((size_t)b * NC + j) * H + h;
    SH[o] = hh;
    hh = SA[o] * hh + SB[o];
  }
}

__global__ __launch_bounds__(256)
void scan_phase3(const uint16_t* __restrict__ gpre, const uint16_t* __restrict__ convb,
                 const float* __restrict__ ap, const float* __restrict__ SH,
                 const uint16_t* __restrict__ left, uint16_t* __restrict__ lr,
                 int S, int H, int T0, int NC)
{
  const int h = blockIdx.x * 256 + threadIdx.x;
  const int j = blockIdx.y, b = blockIdx.z;
  const float coef = -8.f * log1pf(expf(ap[h]));
  float hh = SH[((size_t)b * NC + j) * H + h];
  size_t rowb = (size_t)b * S + (size_t)j * T0;
  for (int t = 0; t < T0; ++t){
    size_t row = rowb + t;
    float rp = bf16_to_f32(gpre[row * 2 * H + h]);
    float ip = bf16_to_f32(gpre[row * 2 * H + H + h]);
    float xc = bf16_to_f32(convb[row * H + h]);
    float a, bb; rglru_ab(rp, ip, xc, coef, a, bb);
    hh = a * hh + bb;
    lr[row * H + h] = f32_to_bf16_rne(bf16_to_f32(left[row * H + h]) * hh);
  }
}

// ---------------------------------------------------------------------------
extern "C" void kernel_launch(void* const* d_in, const int* in_sizes, int n_in,
                              void* d_out, int out_size, void* d_ws, size_t ws_size,
                              hipStream_t stream)
{
  const int B = 2, S = 2048, D = 2048, H = 2048, F = 6144;
  const int M = B * S;            // 4096
  const int NC = 32, T0 = S / NC; // scan chunking

  const float* x       = (const float*)d_in[0];
  const float* norm1_w = (const float*)d_in[1];
  const float* left_W  = (const float*)d_in[2];
  const float* left_b  = (const float*)d_in[3];
  const float* right_W = (const float*)d_in[4];
  const float* right_b = (const float*)d_in[5];
  const float* conv_w  = (const float*)d_in[6];
  const float* conv_b  = (const float*)d_in[7];
  const float* ga_W    = (const float*)d_in[8];
  const float* ga_b    = (const float*)d_in[9];
  const float* gx_W    = (const float*)d_in[10];
  const float* gx_b    = (const float*)d_in[11];
  const float* a_param = (const float*)d_in[12];
  const float* out_W   = (const float*)d_in[13];
  const float* out_b   = (const float*)d_in[14];
  const float* norm2_w = (const float*)d_in[15];
  const float* up1_W   = (const float*)d_in[16];
  const float* up1_b   = (const float*)d_in[17];
  const float* up2_W   = (const float*)d_in[18];
  const float* up2_b   = (const float*)d_in[19];
  const float* down_W  = (const float*)d_in[20];
  const float* down_b  = (const float*)d_in[21];

  char* ws = (char*)d_ws;
  size_t off = 0;
  auto alloc = [&](size_t bytes) -> char* {
    char* p = ws + off; off += (bytes + 255) & ~(size_t)255; return p;
  };
  // Overlays (exact-size, 256-aligned multiples):
  //   T1 [M][F] bf16 === XN + LEFT + RPRE (3 x 16.78 MB), all dead by step 8
  //   G  [M][F] bf16 === CONVB + GPRE (16.78 + 33.55 MB), dead by step 9
  uint16_t* WT    = (uint16_t*)alloc((size_t)F * D * 2);   // weight bf16^T scratch
  uint16_t* XN    = (uint16_t*)alloc((size_t)M * D * 2);   // rmsnorm1 out
  uint16_t* LEFT  = (uint16_t*)alloc((size_t)M * H * 2);   // gelu(left) bf16
  uint16_t* RPRE  = (uint16_t*)alloc((size_t)M * H * 2);   // right preact (conv in)
  uint16_t* CONVB = (uint16_t*)alloc((size_t)M * H * 2);   // conv out
  uint16_t* GPRE  = (uint16_t*)alloc((size_t)M * 2 * H * 2); // [M][2H] r|i preacts
  uint16_t* LR    = (uint16_t*)alloc((size_t)M * H * 2);   // left * h
  float*    X1    = (float*)   alloc((size_t)M * D * 4);   // residual stream (f32)
  uint16_t* X1N   = (uint16_t*)alloc((size_t)M * D * 2);   // rmsnorm2 out
  float*    SA    = (float*)   alloc((size_t)B * NC * H * 4);
  float*    SB    = (float*)   alloc((size_t)B * NC * H * 4);
  float*    SHB   = (float*)   alloc((size_t)B * NC * H * 4);
  uint16_t* T1    = XN;    // overlay: [M][F] bf16, live steps 8-9
  uint16_t* G     = CONVB; // overlay: [M][F] bf16, live steps 9-10

  if (off > ws_size) {
    fprintf(stderr, "kernel_launch: ws too small, need %zu have %zu\n", off, ws_size);
    return;
  }

  float* OUT = (float*)d_out;
  dim3 blk(256);

  // 1. xn = rmsnorm(x)
  rmsnorm_kernel<<<M, blk, 0, stream>>>(x, norm1_w, XN, D);

  // 2. merged left|right GEMM: N=4096, SPLIT=2048 (gelu | raw)
  cvt_transpose<<<dim3(H/64, D/64), blk, 0, stream>>>(left_W, WT, D, H);
  cvt_transpose<<<dim3(H/64, D/64), blk, 0, stream>>>(right_W, WT + (size_t)H * D, D, H);
  gemm_kernel<1><<<dim3((2*H)/128, M/128), blk, 0, stream>>>(
      XN, WT, left_b, right_b, nullptr, nullptr, nullptr, LEFT, RPRE, M, 2*H, D, H);

  // 3. conv (causal depthwise) bf16 -> bf16
  conv_kernel<<<dim3(H/256, S/128, B), blk, 0, stream>>>(RPRE, conv_w, conv_b, CONVB, S, H);

  // 4. merged gate GEMM: GPRE[M][2H] = conv @ [ga_W | gx_W] + [ga_b | gx_b]
  cvt_transpose<<<dim3(H/64, H/64), blk, 0, stream>>>(ga_W, WT, H, H);
  cvt_transpose<<<dim3(H/64, H/64), blk, 0, stream>>>(gx_W, WT + (size_t)H * H, H, H);
  gemm_kernel<2><<<dim3((2*H)/128, M/128), blk, 0, stream>>>(
      CONVB, WT, ga_b, gx_b, nullptr, nullptr, nullptr, GPRE, nullptr, M, 2*H, H, H);

  // 5. rg-lru chunked scan; phase3 fuses lr = bf16(left * h)
  scan_phase1<<<dim3(H/256, NC, B), blk, 0, stream>>>(GPRE, CONVB, a_param, SA, SB, S, H, T0, NC);
  scan_phase2<<<dim3(H/256, B), blk, 0, stream>>>(SA, SB, SHB, H, NC);
  scan_phase3<<<dim3(H/256, NC, B), blk, 0, stream>>>(GPRE, CONVB, a_param, SHB, LEFT, LR, S, H, T0, NC);

  // 6. x1 = lr @ out_W + out_b + x   (f32 residual stream)
  cvt_transpose<<<dim3(D/64, H/64), blk, 0, stream>>>(out_W, WT, H, D);
  gemm_kernel<0><<<dim3(D/128, M/128), blk, 0, stream>>>(
      LR, WT, out_b, out_b, x, nullptr, X1, nullptr, nullptr, M, D, H, D);

  // 7. x1n = rmsnorm(x1)
  rmsnorm_kernel<<<M, blk, 0, stream>>>(X1, norm2_w, X1N, D);

  // 8. t1 = gelu(x1n @ up1_W + up1_b)  (SPLIT=F -> all gelu; overlays XN/LEFT/RPRE)
  cvt_transpose<<<dim3(F/64, D/64), blk, 0, stream>>>(up1_W, WT, D, F);
  gemm_kernel<1><<<dim3(F/128, M/128), blk, 0, stream>>>(
      X1N, WT, up1_b, up1_b, nullptr, nullptr, nullptr, T1, nullptr, M, F, D, F);

  // 9. g = bf16(t1 * (x1n @ up2_W + up2_b))  (overlays CONVB/GPRE)
  cvt_transpose<<<dim3(F/64, D/64), blk, 0, stream>>>(up2_W, WT, D, F);
  gemm_kernel<3><<<dim3(F/128, M/128), blk, 0, stream>>>(
      X1N, WT, up2_b, up2_b, nullptr, T1, nullptr, G, nullptr, M, F, D, F);

  // 10. out = g @ down_W + down_b + x1
  cvt_transpose<<<dim3(D/64, F/64), blk, 0, stream>>>(down_W, WT, F, D);
  gemm_kernel<0><<<dim3(D/128, M/128), blk, 0, stream>>>(
      G, WT, down_b, down_b, X1, nullptr, OUT, nullptr, nullptr, M, D, F, D);
}

// Round 8
// 819.333 us; speedup vs baseline: 1.0701x; 1.0701x over previous
//
#include <hip/hip_runtime.h>
#include <cstdint>
#include <cstdio>

typedef __bf16 bf16x8 __attribute__((ext_vector_type(8)));
typedef float  f32x4  __attribute__((ext_vector_type(4)));
typedef const __attribute__((address_space(1))) void* gas_ptr;
typedef __attribute__((address_space(3))) void* las_ptr;

__device__ __forceinline__ uint16_t f32_to_bf16_rne(float f){
  uint32_t u = __builtin_bit_cast(uint32_t, f);
  u += 0x7FFFu + ((u >> 16) & 1u);
  return (uint16_t)(u >> 16);
}
__device__ __forceinline__ float bf16_to_f32(uint16_t h){
  uint32_t u = (uint32_t)h << 16;
  return __builtin_bit_cast(float, u);
}
__device__ __forceinline__ float gelu_exact(float x){
  return 0.5f * x * (1.f + erff(x * 0.7071067811865475f));
}

// ---------------------------------------------------------------------------
// 2-phase GEMM (T3-minimum recipe, m230/m248-evidenced): C = A * Bt^T + bias.
// BM x 256 tile, BK=64, 512 threads = 8 waves (2M x 4N), per-wave (BM/2) x 64.
// Per K-tile: {STAGE next tile -> ds_read cur -> setprio(1) MFMA setprio(0)
//              -> vmcnt(0) -> s_barrier}. ONE barrier + one vmcnt per tile
// (vs 2 barriers + full drain per BK=32 in the m97 structure = 1/4 the sync).
// Plain loads/MFMA: compiler schedules lgkmcnt itself (m97 evidence); no
// sched_barrier (m141), no manual lgkm waits.
// LDS: linear dest for global_load_lds; global source chunk pre-swizzled
// gs = c ^ (row&7); reads XOR the same involution (G21, verified r5/r6).
// EPI 0: Cf = v + auxF      EPI 1: col<SPLIT ? Cb0=gelu : Cb1=raw
// EPI 2: Cb0 = v            EPI 3: Cb0 = v * auxB
// ---------------------------------------------------------------------------
template<int EPI, int BM>
__global__ __launch_bounds__(512)
void gemm2p(const uint16_t* __restrict__ A, const uint16_t* __restrict__ Bt,
            const float* __restrict__ bias0, const float* __restrict__ bias1,
            const float* __restrict__ auxF, const uint16_t* __restrict__ auxB,
            float* __restrict__ Cf, uint16_t* __restrict__ Cb0, uint16_t* __restrict__ Cb1,
            int M, int N, int K, int SPLIT)
{
  constexpr int BN = 256;
  constexpr int M_REP   = BM / 32;     // 8 (BM=256) or 4 (BM=128)
  constexpr int LOADS_A = BM / 64;     // 4 or 2
  constexpr int LOADS_B = BN / 64;     // 4
  constexpr int ABYTES  = 2 * BM * 128;   // two A buffers
  __shared__ alignas(16) char smem[2 * (BM + BN) * 128];

  const int tid  = threadIdx.x;
  const int lane = tid & 63;
  const int wid  = tid >> 6;
  const int wm = wid >> 2, wn = wid & 3;
  const int la = lane & 15, lq = lane >> 4;
  const int n0 = blockIdx.x * BN;
  const int m0 = blockIdx.y * BM;

  // staging: thread t covers slot (l*512+t); row rt = l*64 + (t>>3), phys
  // chunk (t&7). LDS linear; global source chunk gs = (t&7) ^ (rt&7).
  const int rt = tid >> 3;
  const int gs = (tid & 7) ^ (rt & 7);
  const uint16_t* srcA = A  + (size_t)(m0 + rt) * K + gs * 8;
  const uint16_t* srcB = Bt + (size_t)(n0 + rt) * K + gs * 8;

  // reads: logical chunk c = kk*4+lq at row -> phys = c ^ (row&7); row&7 = la&7.
  const int rowAb = (wm * (BM / 2) + la) * 128;
  const int rowBb = (wn * 64 + la) * 128;
  const int ck0 = ((lq)     ^ (la & 7)) * 16;   // kk = 0
  const int ck1 = ((4 + lq) ^ (la & 7)) * 16;   // kk = 1

  f32x4 acc[M_REP][4];
  const f32x4 fz = {0.f, 0.f, 0.f, 0.f};
#pragma unroll
  for (int m = 0; m < M_REP; ++m)
#pragma unroll
    for (int n = 0; n < 4; ++n) acc[m][n] = fz;

  const int NT = K >> 6;

#define STAGE(KT, BUF) do {                                                   \
    const uint16_t* sa_ = srcA + (size_t)(KT) * 64;                           \
    const uint16_t* sb_ = srcB + (size_t)(KT) * 64;                           \
    _Pragma("unroll")                                                         \
    for (int l = 0; l < LOADS_A; ++l)                                         \
      __builtin_amdgcn_global_load_lds((gas_ptr)(sa_ + (size_t)l * 64 * K),   \
          (las_ptr)(smem + (BUF) * BM * 128 + (l * 512 + tid) * 16), 16, 0, 0);\
    _Pragma("unroll")                                                         \
    for (int l = 0; l < LOADS_B; ++l)                                         \
      __builtin_amdgcn_global_load_lds((gas_ptr)(sb_ + (size_t)l * 64 * K),   \
          (las_ptr)(smem + ABYTES + (BUF) * BN * 128 + (l * 512 + tid) * 16), \
          16, 0, 0);                                                          \
  } while (0)

  // prologue: stage tile 0, publish
  STAGE(0, 0);
  asm volatile("s_waitcnt vmcnt(0)" ::: "memory");
  __builtin_amdgcn_s_barrier();

  int cur = 0;
  for (int kt = 0; kt < NT; ++kt) {
    const bool pf = (kt + 1 < NT);
    if (pf) STAGE(kt + 1, cur ^ 1);           // issue next-tile loads first

    const char* bufA = smem + cur * BM * 128;
    const char* bufB = smem + ABYTES + cur * BN * 128;

    bf16x8 bF[4][2];
#pragma unroll
    for (int n = 0; n < 4; ++n) {
      int ro = (int)(bufB - smem) + rowBb + n * 2048;
      bF[n][0] = *(const bf16x8*)(smem + ro + ck0);
      bF[n][1] = *(const bf16x8*)(smem + ro + ck1);
    }
    __builtin_amdgcn_s_setprio(1);
#pragma unroll
    for (int m = 0; m < M_REP; ++m) {
      int ro = (int)(bufA - smem) + rowAb + m * 2048;
      bf16x8 a0 = *(const bf16x8*)(smem + ro + ck0);
      bf16x8 a1 = *(const bf16x8*)(smem + ro + ck1);
#pragma unroll
      for (int n = 0; n < 4; ++n) {
        acc[m][n] = __builtin_amdgcn_mfma_f32_16x16x32_bf16(a0, bF[n][0], acc[m][n], 0, 0, 0);
        acc[m][n] = __builtin_amdgcn_mfma_f32_16x16x32_bf16(a1, bF[n][1], acc[m][n], 0, 0, 0);
      }
    }
    __builtin_amdgcn_s_setprio(0);

    if (pf) {
      asm volatile("s_waitcnt vmcnt(0)" ::: "memory");  // next tile landed
      __builtin_amdgcn_s_barrier();                     // publish to all waves
      cur ^= 1;
    }
  }
#undef STAGE

  // epilogue: row = m0 + wm*(BM/2) + m*16 + lq*4 + r, col = n0 + wn*64 + n*16 + la
#pragma unroll
  for (int n = 0; n < 4; ++n) {
    int col = n0 + wn * 64 + n * 16 + la;
    const bool second = (col >= SPLIT);
    float bv = second ? bias1[col - SPLIT] : bias0[col];
#pragma unroll
    for (int m = 0; m < M_REP; ++m) {
      int rbase = m0 + wm * (BM / 2) + m * 16 + lq * 4;
#pragma unroll
      for (int r = 0; r < 4; ++r) {
        int row = rbase + r;
        size_t idx = (size_t)row * N + col;
        float v = acc[m][n][r] + bv;
        if constexpr (EPI == 0) Cf[idx] = v + auxF[idx];
        if constexpr (EPI == 1) {
          if (!second) Cb0[(size_t)row * SPLIT + col] = f32_to_bf16_rne(gelu_exact(v));
          else         Cb1[(size_t)row * (N - SPLIT) + (col - SPLIT)] = f32_to_bf16_rne(v);
        }
        if constexpr (EPI == 2) Cb0[idx] = f32_to_bf16_rne(v);
        if constexpr (EPI == 3) Cb0[idx] = f32_to_bf16_rne(v * bf16_to_f32(auxB[idx]));
      }
    }
  }
}

// ---------------------------------------------------------------------------
// Convert + transpose: in[R][C] f32 -> out[C][R] bf16. 64x64 tiles.
// ---------------------------------------------------------------------------
__global__ __launch_bounds__(256)
void cvt_transpose(const float* __restrict__ in, uint16_t* __restrict__ out, int R, int C)
{
  __shared__ float tile[64][65];
  const int r0 = blockIdx.y * 64, c0 = blockIdx.x * 64;
  const int t = threadIdx.x;
  const int lc = (t & 15) * 4;
  const int lr0 = t >> 4;
#pragma unroll
  for (int j = 0; j < 4; j++){
    int lr = lr0 + j*16;
    float4 v = *(const float4*)(in + (size_t)(r0 + lr) * C + c0 + lc);
    tile[lr][lc+0] = v.x; tile[lr][lc+1] = v.y; tile[lr][lc+2] = v.z; tile[lr][lc+3] = v.w;
  }
  __syncthreads();
  const int oc = t >> 2;
  const int rseg = (t & 3) * 16;
  alignas(16) uint16_t tmp[16];
#pragma unroll
  for (int j = 0; j < 16; j++) tmp[j] = f32_to_bf16_rne(tile[rseg + j][oc]);
  uint4* dst = (uint4*)(out + (size_t)(c0 + oc) * R + r0 + rseg);
  dst[0] = *(const uint4*)(&tmp[0]);
  dst[1] = *(const uint4*)(&tmp[8]);
}

// ---------------------------------------------------------------------------
// RMSNorm: per row of D f32 -> bf16. grid = rows, block = 256 (8 elems/thread).
// ---------------------------------------------------------------------------
__global__ __launch_bounds__(256)
void rmsnorm_kernel(const float* __restrict__ x, const float* __restrict__ w,
                    uint16_t* __restrict__ out, int D)
{
  const int row = blockIdx.x;
  const float* xr = x + (size_t)row * D;
  const int base = threadIdx.x * 8;
  float4 va = *(const float4*)(xr + base);
  float4 vb = *(const float4*)(xr + base + 4);
  float ss = va.x*va.x + va.y*va.y + va.z*va.z + va.w*va.w
           + vb.x*vb.x + vb.y*vb.y + vb.z*vb.z + vb.w*vb.w;
#pragma unroll
  for (int o = 32; o > 0; o >>= 1) ss += __shfl_xor(ss, o);
  __shared__ float red[4];
  if ((threadIdx.x & 63) == 0) red[threadIdx.x >> 6] = ss;
  __syncthreads();
  float tot = red[0] + red[1] + red[2] + red[3];
  float inv = rsqrtf(tot / (float)D + 1e-8f);
  float4 wa = *(const float4*)(w + base);
  float4 wb = *(const float4*)(w + base + 4);
  alignas(16) uint16_t tmp[8];
  tmp[0] = f32_to_bf16_rne(va.x * wa.x * inv);
  tmp[1] = f32_to_bf16_rne(va.y * wa.y * inv);
  tmp[2] = f32_to_bf16_rne(va.z * wa.z * inv);
  tmp[3] = f32_to_bf16_rne(va.w * wa.w * inv);
  tmp[4] = f32_to_bf16_rne(vb.x * wb.x * inv);
  tmp[5] = f32_to_bf16_rne(vb.y * wb.y * inv);
  tmp[6] = f32_to_bf16_rne(vb.z * wb.z * inv);
  tmp[7] = f32_to_bf16_rne(vb.w * wb.w * inv);
  *(uint4*)(out + (size_t)row * D + base) = *(const uint4*)tmp;
}

// ---------------------------------------------------------------------------
// Depthwise causal conv K=4 along t, bf16 in/out. grid (H/256, S/128, B)
// ---------------------------------------------------------------------------
__global__ __launch_bounds__(256)
void conv_kernel(const uint16_t* __restrict__ xin, const float* __restrict__ cw,
                 const float* __restrict__ cb, uint16_t* __restrict__ yout,
                 int S, int H)
{
  const int h = blockIdx.x * 256 + threadIdx.x;
  const int b = blockIdx.z;
  const int t0 = blockIdx.y * 128;
  const float w0 = cw[h], w1 = cw[H + h], w2 = cw[2*H + h], w3 = cw[3*H + h];
  const float bias = cb[h];
  const size_t colbase = (size_t)b * S * H + h;
  float xm3 = (t0 >= 3) ? bf16_to_f32(xin[colbase + (size_t)(t0-3)*H]) : 0.f;
  float xm2 = (t0 >= 2) ? bf16_to_f32(xin[colbase + (size_t)(t0-2)*H]) : 0.f;
  float xm1 = (t0 >= 1) ? bf16_to_f32(xin[colbase + (size_t)(t0-1)*H]) : 0.f;
  for (int t = t0; t < t0 + 128; ++t){
    size_t idx = colbase + (size_t)t * H;
    float xt = bf16_to_f32(xin[idx]);
    float y = w0*xm3 + w1*xm2 + w2*xm1 + w3*xt + bias;
    yout[idx] = f32_to_bf16_rne(y);
    xm3 = xm2; xm2 = xm1; xm1 = xt;
  }
}

// ---------------------------------------------------------------------------
// RG-LRU chunked scan over bf16 inputs. gpre[M][2H]: col h = r-preact,
// col H+h = i-preact. convb[M][H] = conv output (the x of the LRU).
// ---------------------------------------------------------------------------
__device__ __forceinline__ void rglru_ab(float rp, float ip, float xc, float coef,
                                         float& a, float& bb)
{
  float r  = 1.f / (1.f + expf(-rp));
  float la = coef * r;
  a = expf(la);
  float mult = sqrtf(-expm1f(2.f * la));
  float ig = 1.f / (1.f + expf(-ip));
  bb = mult * ig * xc;
}

__global__ __launch_bounds__(256)
void scan_phase1(const uint16_t* __restrict__ gpre, const uint16_t* __restrict__ convb,
                 const float* __restrict__ ap,
                 float* __restrict__ SA, float* __restrict__ SB,
                 int S, int H, int T0, int NC)
{
  const int h = blockIdx.x * 256 + threadIdx.x;
  const int j = blockIdx.y, b = blockIdx.z;
  const float coef = -8.f * log1pf(expf(ap[h]));
  size_t rowb = (size_t)b * S + (size_t)j * T0;
  float A = 1.f, Bc = 0.f;
  for (int t = 0; t < T0; ++t){
    size_t row = rowb + t;
    float rp = bf16_to_f32(gpre[row * 2 * H + h]);
    float ip = bf16_to_f32(gpre[row * 2 * H + H + h]);
    float xc = bf16_to_f32(convb[row * H + h]);
    float a, bb; rglru_ab(rp, ip, xc, coef, a, bb);
    A *= a; Bc = a * Bc + bb;
  }
  size_t o = ((size_t)b * NC + j) * H + h;
  SA[o] = A; SB[o] = Bc;
}

__global__ __launch_bounds__(256)
void scan_phase2(const float* __restrict__ SA, const float* __restrict__ SB,
                 float* __restrict__ SH, int H, int NC)
{
  const int h = blockIdx.x * 256 + threadIdx.x;
  const int b = blockIdx.y;
  float hh = 0.f;
  for (int j = 0; j < NC; ++j){
    size_t o = ((size_t)b * NC + j) * H + h;
    SH[o] = hh;
    hh = SA[o] * hh + SB[o];
  }
}

__global__ __launch_bounds__(256)
void scan_phase3(const uint16_t* __restrict__ gpre, const uint16_t* __restrict__ convb,
                 const float* __restrict__ ap, const float* __restrict__ SH,
                 const uint16_t* __restrict__ left, uint16_t* __restrict__ lr,
                 int S, int H, int T0, int NC)
{
  const int h = blockIdx.x * 256 + threadIdx.x;
  const int j = blockIdx.y, b = blockIdx.z;
  const float coef = -8.f * log1pf(expf(ap[h]));
  float hh = SH[((size_t)b * NC + j) * H + h];
  size_t rowb = (size_t)b * S + (size_t)j * T0;
  for (int t = 0; t < T0; ++t){
    size_t row = rowb + t;
    float rp = bf16_to_f32(gpre[row * 2 * H + h]);
    float ip = bf16_to_f32(gpre[row * 2 * H + H + h]);
    float xc = bf16_to_f32(convb[row * H + h]);
    float a, bb; rglru_ab(rp, ip, xc, coef, a, bb);
    hh = a * hh + bb;
    lr[row * H + h] = f32_to_bf16_rne(bf16_to_f32(left[row * H + h]) * hh);
  }
}

// ---------------------------------------------------------------------------
extern "C" void kernel_launch(void* const* d_in, const int* in_sizes, int n_in,
                              void* d_out, int out_size, void* d_ws, size_t ws_size,
                              hipStream_t stream)
{
  const int B = 2, S = 2048, D = 2048, H = 2048, F = 6144;
  const int M = B * S;            // 4096
  const int NC = 32, T0 = S / NC; // scan chunking

  const float* x       = (const float*)d_in[0];
  const float* norm1_w = (const float*)d_in[1];
  const float* left_W  = (const float*)d_in[2];
  const float* left_b  = (const float*)d_in[3];
  const float* right_W = (const float*)d_in[4];
  const float* right_b = (const float*)d_in[5];
  const float* conv_w  = (const float*)d_in[6];
  const float* conv_b  = (const float*)d_in[7];
  const float* ga_W    = (const float*)d_in[8];
  const float* ga_b    = (const float*)d_in[9];
  const float* gx_W    = (const float*)d_in[10];
  const float* gx_b    = (const float*)d_in[11];
  const float* a_param = (const float*)d_in[12];
  const float* out_W   = (const float*)d_in[13];
  const float* out_b   = (const float*)d_in[14];
  const float* norm2_w = (const float*)d_in[15];
  const float* up1_W   = (const float*)d_in[16];
  const float* up1_b   = (const float*)d_in[17];
  const float* up2_W   = (const float*)d_in[18];
  const float* up2_b   = (const float*)d_in[19];
  const float* down_W  = (const float*)d_in[20];
  const float* down_b  = (const float*)d_in[21];

  char* ws = (char*)d_ws;
  size_t off = 0;
  auto alloc = [&](size_t bytes) -> char* {
    char* p = ws + off; off += (bytes + 255) & ~(size_t)255; return p;
  };
  // Overlays (exact-size, 256-aligned multiples):
  //   T1 [M][F] bf16 === XN + LEFT + RPRE (3 x 16.78 MB), all dead by step 8
  //   G  [M][F] bf16 === CONVB + GPRE (16.78 + 33.55 MB), dead by step 9
  uint16_t* WT    = (uint16_t*)alloc((size_t)F * D * 2);   // weight bf16^T scratch
  uint16_t* XN    = (uint16_t*)alloc((size_t)M * D * 2);   // rmsnorm1 out
  uint16_t* LEFT  = (uint16_t*)alloc((size_t)M * H * 2);   // gelu(left) bf16
  uint16_t* RPRE  = (uint16_t*)alloc((size_t)M * H * 2);   // right preact (conv in)
  uint16_t* CONVB = (uint16_t*)alloc((size_t)M * H * 2);   // conv out
  uint16_t* GPRE  = (uint16_t*)alloc((size_t)M * 2 * H * 2); // [M][2H] r|i preacts
  uint16_t* LR    = (uint16_t*)alloc((size_t)M * H * 2);   // left * h
  float*    X1    = (float*)   alloc((size_t)M * D * 4);   // residual stream (f32)
  uint16_t* X1N   = (uint16_t*)alloc((size_t)M * D * 2);   // rmsnorm2 out
  float*    SA    = (float*)   alloc((size_t)B * NC * H * 4);
  float*    SB    = (float*)   alloc((size_t)B * NC * H * 4);
  float*    SHB   = (float*)   alloc((size_t)B * NC * H * 4);
  uint16_t* T1    = XN;    // overlay: [M][F] bf16, live steps 8-9
  uint16_t* G     = CONVB; // overlay: [M][F] bf16, live steps 9-10

  if (off > ws_size) {
    fprintf(stderr, "kernel_launch: ws too small, need %zu have %zu\n", off, ws_size);
    return;
  }

  float* OUT = (float*)d_out;
  dim3 blk(256);
  dim3 gblk(512);

  // 1. xn = rmsnorm(x)
  rmsnorm_kernel<<<M, blk, 0, stream>>>(x, norm1_w, XN, D);

  // 2. merged left|right GEMM: N=4096, SPLIT=2048 (gelu | raw)
  cvt_transpose<<<dim3(H/64, D/64), blk, 0, stream>>>(left_W, WT, D, H);
  cvt_transpose<<<dim3(H/64, D/64), blk, 0, stream>>>(right_W, WT + (size_t)H * D, D, H);
  gemm2p<1, 256><<<dim3((2*H)/256, M/256), gblk, 0, stream>>>(
      XN, WT, left_b, right_b, nullptr, nullptr, nullptr, LEFT, RPRE, M, 2*H, D, H);

  // 3. conv (causal depthwise) bf16 -> bf16
  conv_kernel<<<dim3(H/256, S/128, B), blk, 0, stream>>>(RPRE, conv_w, conv_b, CONVB, S, H);

  // 4. merged gate GEMM: GPRE[M][2H] = conv @ [ga_W | gx_W] + [ga_b | gx_b]
  cvt_transpose<<<dim3(H/64, H/64), blk, 0, stream>>>(ga_W, WT, H, H);
  cvt_transpose<<<dim3(H/64, H/64), blk, 0, stream>>>(gx_W, WT + (size_t)H * H, H, H);
  gemm2p<2, 256><<<dim3((2*H)/256, M/256), gblk, 0, stream>>>(
      CONVB, WT, ga_b, gx_b, nullptr, nullptr, nullptr, GPRE, nullptr, M, 2*H, H, H);

  // 5. rg-lru chunked scan; phase3 fuses lr = bf16(left * h)
  scan_phase1<<<dim3(H/256, NC, B), blk, 0, stream>>>(GPRE, CONVB, a_param, SA, SB, S, H, T0, NC);
  scan_phase2<<<dim3(H/256, B), blk, 0, stream>>>(SA, SB, SHB, H, NC);
  scan_phase3<<<dim3(H/256, NC, B), blk, 0, stream>>>(GPRE, CONVB, a_param, SHB, LEFT, LR, S, H, T0, NC);

  // 6. x1 = lr @ out_W + out_b + x   (f32 residual; BM=128 keeps grid at 256)
  cvt_transpose<<<dim3(D/64, H/64), blk, 0, stream>>>(out_W, WT, H, D);
  gemm2p<0, 128><<<dim3(D/256, M/128), gblk, 0, stream>>>(
      LR, WT, out_b, out_b, x, nullptr, X1, nullptr, nullptr, M, D, H, D);

  // 7. x1n = rmsnorm(x1)
  rmsnorm_kernel<<<M, blk, 0, stream>>>(X1, norm2_w, X1N, D);

  // 8. t1 = gelu(x1n @ up1_W + up1_b)  (SPLIT=F -> all gelu; overlays XN/LEFT/RPRE)
  cvt_transpose<<<dim3(F/64, D/64), blk, 0, stream>>>(up1_W, WT, D, F);
  gemm2p<1, 256><<<dim3(F/256, M/256), gblk, 0, stream>>>(
      X1N, WT, up1_b, up1_b, nullptr, nullptr, nullptr, T1, nullptr, M, F, D, F);

  // 9. g = bf16(t1 * (x1n @ up2_W + up2_b))  (overlays CONVB/GPRE)
  cvt_transpose<<<dim3(F/64, D/64), blk, 0, stream>>>(up2_W, WT, D, F);
  gemm2p<3, 256><<<dim3(F/256, M/256), gblk, 0, stream>>>(
      X1N, WT, up2_b, up2_b, nullptr, T1, nullptr, G, nullptr, M, F, D, F);

  // 10. out = g @ down_W + down_b + x1  (BM=128, K=6144)
  cvt_transpose<<<dim3(D/64, F/64), blk, 0, stream>>>(down_W, WT, F, D);
  gemm2p<0, 128><<<dim3(D/256, M/128), gblk, 0, stream>>>(
      G, WT, down_b, down_b, X1, nullptr, OUT, nullptr, nullptr, M, D, F, D);
}

// Round 9
// 782.830 us; speedup vs baseline: 1.1200x; 1.0466x over previous
//
#include <hip/hip_runtime.h>
#include <cstdint>
#include <cstdio>

typedef __bf16 bf16x8 __attribute__((ext_vector_type(8)));
typedef float  f32x4  __attribute__((ext_vector_type(4)));
typedef const __attribute__((address_space(1))) void* gas_ptr;
typedef __attribute__((address_space(3))) void* las_ptr;

__device__ __forceinline__ uint16_t f32_to_bf16_rne(float f){
  uint32_t u = __builtin_bit_cast(uint32_t, f);
  u += 0x7FFFu + ((u >> 16) & 1u);
  return (uint16_t)(u >> 16);
}
__device__ __forceinline__ float bf16_to_f32(uint16_t h){
  uint32_t u = (uint32_t)h << 16;
  return __builtin_bit_cast(float, u);
}
__device__ __forceinline__ float gelu_exact(float x){
  return 0.5f * x * (1.f + erff(x * 0.7071067811865475f));
}

// Shared epilogue element. EPI:
// 1: col<SPLIT ? Cb0=bf16(gelu(v)) [stride SPLIT] : Cb1=bf16(v) [stride N-SPLIT]
// 2: Cb0[idx] = bf16(v)
// 4: Cb0[idx] = bf16(v + auxF[idx])        (f32 residual in, bf16 out)
// 5: Cf[idx]  = v + f32(auxB[idx])         (bf16 residual in, f32 out)
template<int EPI>
__device__ __forceinline__ void epi_store(float v, size_t idx, int row, int col,
    int N, int SPLIT, const float* auxF, const uint16_t* auxB,
    float* Cf, uint16_t* Cb0, uint16_t* Cb1, bool second)
{
  if constexpr (EPI == 1) {
    if (!second) Cb0[(size_t)row * SPLIT + col] = f32_to_bf16_rne(gelu_exact(v));
    else         Cb1[(size_t)row * (N - SPLIT) + (col - SPLIT)] = f32_to_bf16_rne(v);
  }
  if constexpr (EPI == 2) Cb0[idx] = f32_to_bf16_rne(v);
  if constexpr (EPI == 4) Cb0[idx] = f32_to_bf16_rne(v + auxF[idx]);
  if constexpr (EPI == 5) Cf[idx] = v + bf16_to_f32(auxB[idx]);
}

// ---------------------------------------------------------------------------
// 8-phase GEMM (m201-faithful; r6 minus its two confounds: no XCD swizzle,
// no manual lgkmcnt — compiler inserts fine-grained waits). 256x256 tile,
// BK=64, 512 threads = 8 waves (2M x 4N). Per K-tile: 4 phases, each
// {ds_reads ; (stage at p2/p3) ; barrier ; setprio(1) 16xMFMA setprio(0) ;
//  barrier}; counted vmcnt(8) ONCE per tile (allows next tile's 8 staging
// loads to fly across the boundary — T4). Conflict-free chunk-XOR LDS with
// pre-swizzled global source (G21).
// ---------------------------------------------------------------------------
template<int EPI>
__global__ __launch_bounds__(512)
void gemm8p(const uint16_t* __restrict__ A, const uint16_t* __restrict__ Bt,
            const float* __restrict__ bias0, const float* __restrict__ bias1,
            const float* __restrict__ auxF, const uint16_t* __restrict__ auxB,
            float* __restrict__ Cf, uint16_t* __restrict__ Cb0, uint16_t* __restrict__ Cb1,
            int M, int N, int K, int SPLIT)
{
  __shared__ alignas(16) char smem[131072];   // A: 2x32KB @0, B: 2x32KB @64KB
  const int tid = threadIdx.x, lane = tid & 63, wid = tid >> 6;
  const int wm = wid >> 2, wn = wid & 3;
  const int la = lane & 15, lq = lane >> 4;
  const int n0 = blockIdx.x * 256, m0 = blockIdx.y * 256;

  // staging: thread t -> slot (l*512+t), row rt = l*64 + (t>>3), chunk t&7;
  // LDS linear, global source chunk gs = (t&7) ^ (rt&7).
  const int rt = tid >> 3;
  const int gs = (tid & 7) ^ (rt & 7);
  const uint16_t* srcA = A  + (size_t)(m0 + rt) * K + gs * 8;
  const uint16_t* srcB = Bt + (size_t)(n0 + rt) * K + gs * 8;

  // reads: logical chunk (kk*4+lq) at row -> phys ^ (row&7); row&7 == la&7.
  const int rowAb = (wm * 128 + la) * 128;
  const int rowBb = (wn * 64 + la) * 128;
  const int ck0 = ((lq)     ^ (la & 7)) * 16;
  const int ck1 = ((4 + lq) ^ (la & 7)) * 16;

  f32x4 acc[8][4];
  const f32x4 fz = {0.f, 0.f, 0.f, 0.f};
#pragma unroll
  for (int m = 0; m < 8; ++m)
#pragma unroll
    for (int n = 0; n < 4; ++n) acc[m][n] = fz;

  bf16x8 aF[4][2], bF0[2][2], bF1[2][2];
  const int NT = K >> 6;

#define STAGE_A8(KT, BUF) do { _Pragma("unroll")                              \
    for (int l = 0; l < 4; ++l)                                               \
      __builtin_amdgcn_global_load_lds(                                       \
          (gas_ptr)(srcA + (size_t)(KT) * 64 + (size_t)l * 64 * K),           \
          (las_ptr)(smem + (BUF) * 32768 + (l * 512 + tid) * 16), 16, 0, 0);  \
  } while (0)
#define STAGE_B8(KT, BUF) do { _Pragma("unroll")                              \
    for (int l = 0; l < 4; ++l)                                               \
      __builtin_amdgcn_global_load_lds(                                       \
          (gas_ptr)(srcB + (size_t)(KT) * 64 + (size_t)l * 64 * K),           \
          (las_ptr)(smem + 65536 + (BUF) * 32768 + (l * 512 + tid) * 16),     \
          16, 0, 0);                                                          \
  } while (0)
#define RD_B8(DST, NH, BUF) do { _Pragma("unroll")                            \
    for (int nq = 0; nq < 2; ++nq) {                                          \
      int ro_ = 65536 + (BUF) * 32768 + rowBb + ((NH) * 2 + nq) * 2048;       \
      DST[nq][0] = *(const bf16x8*)(smem + ro_ + ck0);                        \
      DST[nq][1] = *(const bf16x8*)(smem + ro_ + ck1);                        \
    }                                                                         \
  } while (0)
#define RD_A8(MHS, BUF) do { _Pragma("unroll")                                \
    for (int mq = 0; mq < 4; ++mq) {                                          \
      int ro_ = (BUF) * 32768 + rowAb + ((MHS) * 4 + mq) * 2048;              \
      aF[mq][0] = *(const bf16x8*)(smem + ro_ + ck0);                         \
      aF[mq][1] = *(const bf16x8*)(smem + ro_ + ck1);                         \
    }                                                                         \
  } while (0)
#define MM8(MHS, NH, BF) do { _Pragma("unroll")                               \
    for (int mq = 0; mq < 4; ++mq)                                            \
      _Pragma("unroll")                                                       \
      for (int nq = 0; nq < 2; ++nq) {                                        \
        acc[(MHS)*4+mq][(NH)*2+nq] = __builtin_amdgcn_mfma_f32_16x16x32_bf16( \
            aF[mq][0], BF[nq][0], acc[(MHS)*4+mq][(NH)*2+nq], 0, 0, 0);       \
        acc[(MHS)*4+mq][(NH)*2+nq] = __builtin_amdgcn_mfma_f32_16x16x32_bf16( \
            aF[mq][1], BF[nq][1], acc[(MHS)*4+mq][(NH)*2+nq], 0, 0, 0);       \
      }                                                                       \
  } while (0)
#define BARR() __builtin_amdgcn_s_barrier()

  // prologue: stage tiles 0,1; counted wait (tile 0 landed, tile 1 in flight)
  STAGE_A8(0, 0); STAGE_B8(0, 0);
  STAGE_A8(1, 1); STAGE_B8(1, 1);
  asm volatile("s_waitcnt vmcnt(8)" ::: "memory");
  BARR();

  for (int t = 0; t < NT; ++t) {
    const int buf = t & 1;
    const bool pf = (t + 2 < NT);
    // p0: read B half0 + A half0 -> MFMA (0,0)
    RD_B8(bF0, 0, buf); RD_A8(0, buf);
    BARR();
    __builtin_amdgcn_s_setprio(1); MM8(0, 0, bF0); __builtin_amdgcn_s_setprio(0);
    BARR();
    // p1: read B half1 -> MFMA (0,1)
    RD_B8(bF1, 1, buf);
    BARR();
    __builtin_amdgcn_s_setprio(1); MM8(0, 1, bF1); __builtin_amdgcn_s_setprio(0);
    BARR();
    // p2: read A half1; stage B(t+2) over buf-B (B reads done p0/p1)
    RD_A8(1, buf);
    if (pf) STAGE_B8(t + 2, buf);
    BARR();
    __builtin_amdgcn_s_setprio(1); MM8(1, 0, bF0); __builtin_amdgcn_s_setprio(0);
    BARR();
    // p3: stage A(t+2) over buf-A (A reads done p0/p2) -> MFMA (1,1)
    if (pf) STAGE_A8(t + 2, buf);
    BARR();
    __builtin_amdgcn_s_setprio(1); MM8(1, 1, bF1); __builtin_amdgcn_s_setprio(0);
    asm volatile("s_waitcnt vmcnt(8)" ::: "memory");   // counted, never 0 mid-loop
    BARR();
  }
#undef STAGE_A8
#undef STAGE_B8
#undef RD_B8
#undef RD_A8
#undef MM8
#undef BARR

  // epilogue: row = m0 + wm*128 + m*16 + lq*4 + r, col = n0 + wn*64 + n*16 + la
#pragma unroll
  for (int n = 0; n < 4; ++n) {
    int col = n0 + wn * 64 + n * 16 + la;
    const bool second = (col >= SPLIT);
    float bv = second ? bias1[col - SPLIT] : bias0[col];
#pragma unroll
    for (int m = 0; m < 8; ++m) {
      int rbase = m0 + wm * 128 + m * 16 + lq * 4;
#pragma unroll
      for (int r = 0; r < 4; ++r) {
        int row = rbase + r;
        size_t idx = (size_t)row * N + col;
        epi_store<EPI>(acc[m][n][r] + bv, idx, row, col, N, SPLIT, auxF, auxB, Cf, Cb0, Cb1, second);
      }
    }
  }
}

// ---------------------------------------------------------------------------
// 2-phase GEMM (validated r8 = m233 parity). BM x 256, BK=64, 8 waves.
// ---------------------------------------------------------------------------
template<int EPI, int BM>
__global__ __launch_bounds__(512)
void gemm2p(const uint16_t* __restrict__ A, const uint16_t* __restrict__ Bt,
            const float* __restrict__ bias0, const float* __restrict__ bias1,
            const float* __restrict__ auxF, const uint16_t* __restrict__ auxB,
            float* __restrict__ Cf, uint16_t* __restrict__ Cb0, uint16_t* __restrict__ Cb1,
            int M, int N, int K, int SPLIT)
{
  constexpr int BN = 256;
  constexpr int M_REP   = BM / 32;
  constexpr int LOADS_A = BM / 64;
  constexpr int LOADS_B = BN / 64;
  constexpr int ABYTES  = 2 * BM * 128;
  __shared__ alignas(16) char smem[2 * (BM + BN) * 128];

  const int tid  = threadIdx.x;
  const int lane = tid & 63;
  const int wid  = tid >> 6;
  const int wm = wid >> 2, wn = wid & 3;
  const int la = lane & 15, lq = lane >> 4;
  const int n0 = blockIdx.x * BN;
  const int m0 = blockIdx.y * BM;

  const int rt = tid >> 3;
  const int gs = (tid & 7) ^ (rt & 7);
  const uint16_t* srcA = A  + (size_t)(m0 + rt) * K + gs * 8;
  const uint16_t* srcB = Bt + (size_t)(n0 + rt) * K + gs * 8;

  const int rowAb = (wm * (BM / 2) + la) * 128;
  const int rowBb = (wn * 64 + la) * 128;
  const int ck0 = ((lq)     ^ (la & 7)) * 16;
  const int ck1 = ((4 + lq) ^ (la & 7)) * 16;

  f32x4 acc[M_REP][4];
  const f32x4 fz = {0.f, 0.f, 0.f, 0.f};
#pragma unroll
  for (int m = 0; m < M_REP; ++m)
#pragma unroll
    for (int n = 0; n < 4; ++n) acc[m][n] = fz;

  const int NT = K >> 6;

#define STAGE(KT, BUF) do {                                                   \
    const uint16_t* sa_ = srcA + (size_t)(KT) * 64;                           \
    const uint16_t* sb_ = srcB + (size_t)(KT) * 64;                           \
    _Pragma("unroll")                                                         \
    for (int l = 0; l < LOADS_A; ++l)                                         \
      __builtin_amdgcn_global_load_lds((gas_ptr)(sa_ + (size_t)l * 64 * K),   \
          (las_ptr)(smem + (BUF) * BM * 128 + (l * 512 + tid) * 16), 16, 0, 0);\
    _Pragma("unroll")                                                         \
    for (int l = 0; l < LOADS_B; ++l)                                         \
      __builtin_amdgcn_global_load_lds((gas_ptr)(sb_ + (size_t)l * 64 * K),   \
          (las_ptr)(smem + ABYTES + (BUF) * BN * 128 + (l * 512 + tid) * 16), \
          16, 0, 0);                                                          \
  } while (0)

  STAGE(0, 0);
  asm volatile("s_waitcnt vmcnt(0)" ::: "memory");
  __builtin_amdgcn_s_barrier();

  int cur = 0;
  for (int kt = 0; kt < NT; ++kt) {
    const bool pf = (kt + 1 < NT);
    if (pf) STAGE(kt + 1, cur ^ 1);

    const int offA = cur * BM * 128;
    const int offB = ABYTES + cur * BN * 128;

    bf16x8 bF[4][2];
#pragma unroll
    for (int n = 0; n < 4; ++n) {
      int ro = offB + rowBb + n * 2048;
      bF[n][0] = *(const bf16x8*)(smem + ro + ck0);
      bF[n][1] = *(const bf16x8*)(smem + ro + ck1);
    }
    __builtin_amdgcn_s_setprio(1);
#pragma unroll
    for (int m = 0; m < M_REP; ++m) {
      int ro = offA + rowAb + m * 2048;
      bf16x8 a0 = *(const bf16x8*)(smem + ro + ck0);
      bf16x8 a1 = *(const bf16x8*)(smem + ro + ck1);
#pragma unroll
      for (int n = 0; n < 4; ++n) {
        acc[m][n] = __builtin_amdgcn_mfma_f32_16x16x32_bf16(a0, bF[n][0], acc[m][n], 0, 0, 0);
        acc[m][n] = __builtin_amdgcn_mfma_f32_16x16x32_bf16(a1, bF[n][1], acc[m][n], 0, 0, 0);
      }
    }
    __builtin_amdgcn_s_setprio(0);

    if (pf) {
      asm volatile("s_waitcnt vmcnt(0)" ::: "memory");
      __builtin_amdgcn_s_barrier();
      cur ^= 1;
    }
  }
#undef STAGE

#pragma unroll
  for (int n = 0; n < 4; ++n) {
    int col = n0 + wn * 64 + n * 16 + la;
    const bool second = (col >= SPLIT);
    float bv = second ? bias1[col - SPLIT] : bias0[col];
#pragma unroll
    for (int m = 0; m < M_REP; ++m) {
      int rbase = m0 + wm * (BM / 2) + m * 16 + lq * 4;
#pragma unroll
      for (int r = 0; r < 4; ++r) {
        int row = rbase + r;
        size_t idx = (size_t)row * N + col;
        epi_store<EPI>(acc[m][n][r] + bv, idx, row, col, N, SPLIT, auxF, auxB, Cf, Cb0, Cb1, second);
      }
    }
  }
}

// ---------------------------------------------------------------------------
// Convert + transpose: in[R][C] f32 -> out[C][R] bf16. 64x64 tiles.
// ---------------------------------------------------------------------------
__global__ __launch_bounds__(256)
void cvt_transpose(const float* __restrict__ in, uint16_t* __restrict__ out, int R, int C)
{
  __shared__ float tile[64][65];
  const int r0 = blockIdx.y * 64, c0 = blockIdx.x * 64;
  const int t = threadIdx.x;
  const int lc = (t & 15) * 4;
  const int lr0 = t >> 4;
#pragma unroll
  for (int j = 0; j < 4; j++){
    int lr = lr0 + j*16;
    float4 v = *(const float4*)(in + (size_t)(r0 + lr) * C + c0 + lc);
    tile[lr][lc+0] = v.x; tile[lr][lc+1] = v.y; tile[lr][lc+2] = v.z; tile[lr][lc+3] = v.w;
  }
  __syncthreads();
  const int oc = t >> 2;
  const int rseg = (t & 3) * 16;
  alignas(16) uint16_t tmp[16];
#pragma unroll
  for (int j = 0; j < 16; j++) tmp[j] = f32_to_bf16_rne(tile[rseg + j][oc]);
  uint4* dst = (uint4*)(out + (size_t)(c0 + oc) * R + r0 + rseg);
  dst[0] = *(const uint4*)(&tmp[0]);
  dst[1] = *(const uint4*)(&tmp[8]);
}

// ---------------------------------------------------------------------------
// RMSNorm f32-in: per row of D -> bf16.
// ---------------------------------------------------------------------------
__global__ __launch_bounds__(256)
void rmsnorm_kernel(const float* __restrict__ x, const float* __restrict__ w,
                    uint16_t* __restrict__ out, int D)
{
  const int row = blockIdx.x;
  const float* xr = x + (size_t)row * D;
  const int base = threadIdx.x * 8;
  float4 va = *(const float4*)(xr + base);
  float4 vb = *(const float4*)(xr + base + 4);
  float ss = va.x*va.x + va.y*va.y + va.z*va.z + va.w*va.w
           + vb.x*vb.x + vb.y*vb.y + vb.z*vb.z + vb.w*vb.w;
#pragma unroll
  for (int o = 32; o > 0; o >>= 1) ss += __shfl_xor(ss, o);
  __shared__ float red[4];
  if ((threadIdx.x & 63) == 0) red[threadIdx.x >> 6] = ss;
  __syncthreads();
  float tot = red[0] + red[1] + red[2] + red[3];
  float inv = rsqrtf(tot / (float)D + 1e-8f);
  float4 wa = *(const float4*)(w + base);
  float4 wb = *(const float4*)(w + base + 4);
  alignas(16) uint16_t tmp[8];
  tmp[0] = f32_to_bf16_rne(va.x * wa.x * inv);
  tmp[1] = f32_to_bf16_rne(va.y * wa.y * inv);
  tmp[2] = f32_to_bf16_rne(va.z * wa.z * inv);
  tmp[3] = f32_to_bf16_rne(va.w * wa.w * inv);
  tmp[4] = f32_to_bf16_rne(vb.x * wb.x * inv);
  tmp[5] = f32_to_bf16_rne(vb.y * wb.y * inv);
  tmp[6] = f32_to_bf16_rne(vb.z * wb.z * inv);
  tmp[7] = f32_to_bf16_rne(vb.w * wb.w * inv);
  *(uint4*)(out + (size_t)row * D + base) = *(const uint4*)tmp;
}

// ---------------------------------------------------------------------------
// RMSNorm bf16-in: per row of D -> bf16.
// ---------------------------------------------------------------------------
__global__ __launch_bounds__(256)
void rmsnorm_bf16_kernel(const uint16_t* __restrict__ x, const float* __restrict__ w,
                         uint16_t* __restrict__ out, int D)
{
  const int row = blockIdx.x;
  const uint16_t* xr = x + (size_t)row * D;
  const int base = threadIdx.x * 8;
  uint4 v = *(const uint4*)(xr + base);
  const uint16_t* vp = (const uint16_t*)&v;
  float xs[8];
  float ss = 0.f;
#pragma unroll
  for (int j = 0; j < 8; ++j){ xs[j] = bf16_to_f32(vp[j]); ss += xs[j]*xs[j]; }
#pragma unroll
  for (int o = 32; o > 0; o >>= 1) ss += __shfl_xor(ss, o);
  __shared__ float red[4];
  if ((threadIdx.x & 63) == 0) red[threadIdx.x >> 6] = ss;
  __syncthreads();
  float tot = red[0] + red[1] + red[2] + red[3];
  float inv = rsqrtf(tot / (float)D + 1e-8f);
  float4 wa = *(const float4*)(w + base);
  float4 wb = *(const float4*)(w + base + 4);
  float wv[8] = {wa.x, wa.y, wa.z, wa.w, wb.x, wb.y, wb.z, wb.w};
  alignas(16) uint16_t tmp[8];
#pragma unroll
  for (int j = 0; j < 8; ++j) tmp[j] = f32_to_bf16_rne(xs[j] * wv[j] * inv);
  *(uint4*)(out + (size_t)row * D + base) = *(const uint4*)tmp;
}

// ---------------------------------------------------------------------------
// Elementwise multiply in place: t1[i] = bf16(t1[i] * u2[i]). 8 elems/thread.
// ---------------------------------------------------------------------------
__global__ __launch_bounds__(256)
void mul_kernel(uint16_t* __restrict__ t1, const uint16_t* __restrict__ u2)
{
  size_t i = ((size_t)blockIdx.x * 256 + threadIdx.x) * 8;
  uint4 a = *(const uint4*)(t1 + i);
  uint4 b = *(const uint4*)(u2 + i);
  const uint16_t* ap = (const uint16_t*)&a;
  const uint16_t* bp = (const uint16_t*)&b;
  alignas(16) uint16_t o[8];
#pragma unroll
  for (int j = 0; j < 8; ++j)
    o[j] = f32_to_bf16_rne(bf16_to_f32(ap[j]) * bf16_to_f32(bp[j]));
  *(uint4*)(t1 + i) = *(const uint4*)o;
}

// ---------------------------------------------------------------------------
// Depthwise causal conv K=4 along t, bf16 in/out. grid (H/256, S/128, B)
// ---------------------------------------------------------------------------
__global__ __launch_bounds__(256)
void conv_kernel(const uint16_t* __restrict__ xin, const float* __restrict__ cw,
                 const float* __restrict__ cb, uint16_t* __restrict__ yout,
                 int S, int H)
{
  const int h = blockIdx.x * 256 + threadIdx.x;
  const int b = blockIdx.z;
  const int t0 = blockIdx.y * 128;
  const float w0 = cw[h], w1 = cw[H + h], w2 = cw[2*H + h], w3 = cw[3*H + h];
  const float bias = cb[h];
  const size_t colbase = (size_t)b * S * H + h;
  float xm3 = (t0 >= 3) ? bf16_to_f32(xin[colbase + (size_t)(t0-3)*H]) : 0.f;
  float xm2 = (t0 >= 2) ? bf16_to_f32(xin[colbase + (size_t)(t0-2)*H]) : 0.f;
  float xm1 = (t0 >= 1) ? bf16_to_f32(xin[colbase + (size_t)(t0-1)*H]) : 0.f;
  for (int t = t0; t < t0 + 128; ++t){
    size_t idx = colbase + (size_t)t * H;
    float xt = bf16_to_f32(xin[idx]);
    float y = w0*xm3 + w1*xm2 + w2*xm1 + w3*xt + bias;
    yout[idx] = f32_to_bf16_rne(y);
    xm3 = xm2; xm2 = xm1; xm1 = xt;
  }
}

// ---------------------------------------------------------------------------
// RG-LRU chunked scan over bf16 inputs.
// ---------------------------------------------------------------------------
__device__ __forceinline__ void rglru_ab(float rp, float ip, float xc, float coef,
                                         float& a, float& bb)
{
  float r  = 1.f / (1.f + expf(-rp));
  float la = coef * r;
  a = expf(la);
  float mult = sqrtf(-expm1f(2.f * la));
  float ig = 1.f / (1.f + expf(-ip));
  bb = mult * ig * xc;
}

__global__ __launch_bounds__(256)
void scan_phase1(const uint16_t* __restrict__ gpre, const uint16_t* __restrict__ convb,
                 const float* __restrict__ ap,
                 float* __restrict__ SA, float* __restrict__ SB,
                 int S, int H, int T0, int NC)
{
  const int h = blockIdx.x * 256 + threadIdx.x;
  const int j = blockIdx.y, b = blockIdx.z;
  const float coef = -8.f * log1pf(expf(ap[h]));
  size_t rowb = (size_t)b * S + (size_t)j * T0;
  float A = 1.f, Bc = 0.f;
  for (int t = 0; t < T0; ++t){
    size_t row = rowb + t;
    float rp = bf16_to_f32(gpre[row * 2 * H + h]);
    float ip = bf16_to_f32(gpre[row * 2 * H + H + h]);
    float xc = bf16_to_f32(convb[row * H + h]);
    float a, bb; rglru_ab(rp, ip, xc, coef, a, bb);
    A *= a; Bc = a * Bc + bb;
  }
  size_t o = ((size_t)b * NC + j) * H + h;
  SA[o] = A; SB[o] = Bc;
}

__global__ __launch_bounds__(256)
void scan_phase2(const float* __restrict__ SA, const float* __restrict__ SB,
                 float* __restrict__ SH, int H, int NC)
{
  const int h = blockIdx.x * 256 + threadIdx.x;
  const int b = blockIdx.y;
  float hh = 0.f;
  for (int j = 0; j < NC; ++j){
    size_t o = ((size_t)b * NC + j) * H + h;
    SH[o] = hh;
    hh = SA[o] * hh + SB[o];
  }
}

__global__ __launch_bounds__(256)
void scan_phase3(const uint16_t* __restrict__ gpre, const uint16_t* __restrict__ convb,
                 const float* __restrict__ ap, const float* __restrict__ SH,
                 const uint16_t* __restrict__ left, uint16_t* __restrict__ lr,
                 int S, int H, int T0, int NC)
{
  const int h = blockIdx.x * 256 + threadIdx.x;
  const int j = blockIdx.y, b = blockIdx.z;
  const float coef = -8.f * log1pf(expf(ap[h]));
  float hh = SH[((size_t)b * NC + j) * H + h];
  size_t rowb = (size_t)b * S + (size_t)j * T0;
  for (int t = 0; t < T0; ++t){
    size_t row = rowb + t;
    float rp = bf16_to_f32(gpre[row * 2 * H + h]);
    float ip = bf16_to_f32(gpre[row * 2 * H + H + h]);
    float xc = bf16_to_f32(convb[row * H + h]);
    float a, bb; rglru_ab(rp, ip, xc, coef, a, bb);
    hh = a * hh + bb;
    lr[row * H + h] = f32_to_bf16_rne(bf16_to_f32(left[row * H + h]) * hh);
  }
}

// ---------------------------------------------------------------------------
extern "C" void kernel_launch(void* const* d_in, const int* in_sizes, int n_in,
                              void* d_out, int out_size, void* d_ws, size_t ws_size,
                              hipStream_t stream)
{
  const int B = 2, S = 2048, D = 2048, H = 2048, F = 6144;
  const int M = B * S;            // 4096
  const int NC = 32, T0 = S / NC; // scan chunking

  const float* x       = (const float*)d_in[0];
  const float* norm1_w = (const float*)d_in[1];
  const float* left_W  = (const float*)d_in[2];
  const float* left_b  = (const float*)d_in[3];
  const float* right_W = (const float*)d_in[4];
  const float* right_b = (const float*)d_in[5];
  const float* conv_w  = (const float*)d_in[6];
  const float* conv_b  = (const float*)d_in[7];
  const float* ga_W    = (const float*)d_in[8];
  const float* ga_b    = (const float*)d_in[9];
  const float* gx_W    = (const float*)d_in[10];
  const float* gx_b    = (const float*)d_in[11];
  const float* a_param = (const float*)d_in[12];
  const float* out_W   = (const float*)d_in[13];
  const float* out_b   = (const float*)d_in[14];
  const float* norm2_w = (const float*)d_in[15];
  const float* up1_W   = (const float*)d_in[16];
  const float* up1_b   = (const float*)d_in[17];
  const float* up2_W   = (const float*)d_in[18];
  const float* up2_b   = (const float*)d_in[19];
  const float* down_W  = (const float*)d_in[20];
  const float* down_b  = (const float*)d_in[21];

  char* ws = (char*)d_ws;
  size_t off = 0;
  auto alloc = [&](size_t bytes) -> char* {
    char* p = ws + off; off += (bytes + 255) & ~(size_t)255; return p;
  };
  // Overlays (exact-size):
  //   T1 [M][F] bf16 (50.33 MB) === XN + LEFT + RPRE, all dead by step 8
  //   U2 [M][F] bf16 (50.33 MB) === CONVB + GPRE, dead by step 8
  uint16_t* WT    = (uint16_t*)alloc((size_t)2 * F * D * 2); // weights bf16^T (fused up needs 2F x D)
  uint16_t* XN    = (uint16_t*)alloc((size_t)M * D * 2);
  uint16_t* LEFT  = (uint16_t*)alloc((size_t)M * H * 2);
  uint16_t* RPRE  = (uint16_t*)alloc((size_t)M * H * 2);
  uint16_t* CONVB = (uint16_t*)alloc((size_t)M * H * 2);
  uint16_t* GPRE  = (uint16_t*)alloc((size_t)M * 2 * H * 2);
  uint16_t* LR    = (uint16_t*)alloc((size_t)M * H * 2);
  uint16_t* X1B   = (uint16_t*)alloc((size_t)M * D * 2);   // residual x1 (bf16)
  uint16_t* X1N   = (uint16_t*)alloc((size_t)M * D * 2);
  float*    SA    = (float*)   alloc((size_t)B * NC * H * 4);
  float*    SB    = (float*)   alloc((size_t)B * NC * H * 4);
  float*    SHB   = (float*)   alloc((size_t)B * NC * H * 4);
  uint16_t* T1    = XN;    // overlay [M][F], live steps 8-10
  uint16_t* U2    = CONVB; // overlay [M][F], live steps 8-9

  if (off > ws_size) {
    fprintf(stderr, "kernel_launch: ws too small, need %zu have %zu\n", off, ws_size);
    return;
  }

  float* OUT = (float*)d_out;
  dim3 blk(256);
  dim3 gblk(512);

  // 1. xn = rmsnorm(x)
  rmsnorm_kernel<<<M, blk, 0, stream>>>(x, norm1_w, XN, D);

  // 2. merged left|right GEMM (8-phase): N=4096, SPLIT=2048 (gelu | raw)
  cvt_transpose<<<dim3(H/64, D/64), blk, 0, stream>>>(left_W, WT, D, H);
  cvt_transpose<<<dim3(H/64, D/64), blk, 0, stream>>>(right_W, WT + (size_t)H * D, D, H);
  gemm8p<1><<<dim3((2*H)/256, M/256), gblk, 0, stream>>>(
      XN, WT, left_b, right_b, nullptr, nullptr, nullptr, LEFT, RPRE, M, 2*H, D, H);

  // 3. conv (causal depthwise) bf16 -> bf16
  conv_kernel<<<dim3(H/256, S/128, B), blk, 0, stream>>>(RPRE, conv_w, conv_b, CONVB, S, H);

  // 4. merged gate GEMM (8-phase): GPRE[M][2H]
  cvt_transpose<<<dim3(H/64, H/64), blk, 0, stream>>>(ga_W, WT, H, H);
  cvt_transpose<<<dim3(H/64, H/64), blk, 0, stream>>>(gx_W, WT + (size_t)H * H, H, H);
  gemm8p<2><<<dim3((2*H)/256, M/256), gblk, 0, stream>>>(
      CONVB, WT, ga_b, gx_b, nullptr, nullptr, nullptr, GPRE, nullptr, M, 2*H, H, H);

  // 5. rg-lru chunked scan; phase3 fuses lr = bf16(left * h)
  scan_phase1<<<dim3(H/256, NC, B), blk, 0, stream>>>(GPRE, CONVB, a_param, SA, SB, S, H, T0, NC);
  scan_phase2<<<dim3(H/256, B), blk, 0, stream>>>(SA, SB, SHB, H, NC);
  scan_phase3<<<dim3(H/256, NC, B), blk, 0, stream>>>(GPRE, CONVB, a_param, SHB, LEFT, LR, S, H, T0, NC);

  // 6. x1 = bf16(lr @ out_W + out_b + x)   (EPI4, bf16 residual out)
  cvt_transpose<<<dim3(D/64, H/64), blk, 0, stream>>>(out_W, WT, H, D);
  gemm2p<4, 128><<<dim3(D/256, M/128), gblk, 0, stream>>>(
      LR, WT, out_b, out_b, x, nullptr, nullptr, X1B, nullptr, M, D, H, D);

  // 7. x1n = rmsnorm(x1)  (bf16 in)
  rmsnorm_bf16_kernel<<<M, blk, 0, stream>>>(X1B, norm2_w, X1N, D);

  // 8. fused up1|up2 GEMM (8-phase): N=12288, SPLIT=6144 -> T1=gelu(up1), U2=raw(up2)
  //    grid 48x16 = 768 = 3 exact rounds of 256 CUs (no tail).
  cvt_transpose<<<dim3(F/64, D/64), blk, 0, stream>>>(up1_W, WT, D, F);
  cvt_transpose<<<dim3(F/64, D/64), blk, 0, stream>>>(up2_W, WT + (size_t)F * D, D, F);
  gemm8p<1><<<dim3((2*F)/256, M/256), gblk, 0, stream>>>(
      X1N, WT, up1_b, up2_b, nullptr, nullptr, nullptr, T1, U2, M, 2*F, D, F);

  // 9. g = t1 * u2 (in place into T1)
  mul_kernel<<<dim3((unsigned)((size_t)M * F / 8 / 256)), blk, 0, stream>>>(T1, U2);

  // 10. out = g @ down_W + down_b + x1  (EPI5: f32 out, bf16 residual)
  cvt_transpose<<<dim3(D/64, F/64), blk, 0, stream>>>(down_W, WT, F, D);
  gemm2p<5, 128><<<dim3(D/256, M/128), gblk, 0, stream>>>(
      T1, WT, down_b, down_b, nullptr, X1B, OUT, nullptr, nullptr, M, D, F, D);
}

// Round 10
// 730.973 us; speedup vs baseline: 1.1995x; 1.0709x over previous
//
#include <hip/hip_runtime.h>
#include <cstdint>
#include <cstdio>

typedef __bf16 bf16x8 __attribute__((ext_vector_type(8)));
typedef float  f32x4  __attribute__((ext_vector_type(4)));
typedef const __attribute__((address_space(1))) void* gas_ptr;
typedef __attribute__((address_space(3))) void* las_ptr;

__device__ __forceinline__ uint16_t f32_to_bf16_rne(float f){
  uint32_t u = __builtin_bit_cast(uint32_t, f);
  u += 0x7FFFu + ((u >> 16) & 1u);
  return (uint16_t)(u >> 16);
}
__device__ __forceinline__ float bf16_to_f32(uint16_t h){
  uint32_t u = (uint32_t)h << 16;
  return __builtin_bit_cast(float, u);
}
__device__ __forceinline__ float gelu_exact(float x){
  return 0.5f * x * (1.f + erff(x * 0.7071067811865475f));
}

// Shared epilogue element. EPI:
// 1: col<SPLIT ? Cb0=bf16(gelu(v)) [stride SPLIT] : Cb1=bf16(v) [stride N-SPLIT]
// 2: Cb0[idx] = bf16(v)
// 4: Cb0[idx] = bf16(v + auxF[idx])        (f32 residual in, bf16 out)
// 5: Cf[idx]  = v + f32(auxB[idx])         (bf16 residual in, f32 out)
// 6: (gemm8p only) interleaved gated-MLP: see gemm8p epilogue.
template<int EPI>
__device__ __forceinline__ void epi_store(float v, size_t idx, int row, int col,
    int N, int SPLIT, const float* auxF, const uint16_t* auxB,
    float* Cf, uint16_t* Cb0, uint16_t* Cb1, bool second)
{
  if constexpr (EPI == 1) {
    if (!second) Cb0[(size_t)row * SPLIT + col] = f32_to_bf16_rne(gelu_exact(v));
    else         Cb1[(size_t)row * (N - SPLIT) + (col - SPLIT)] = f32_to_bf16_rne(v);
  }
  if constexpr (EPI == 2) Cb0[idx] = f32_to_bf16_rne(v);
  if constexpr (EPI == 4) Cb0[idx] = f32_to_bf16_rne(v + auxF[idx]);
  if constexpr (EPI == 5) Cf[idx] = v + bf16_to_f32(auxB[idx]);
}

// ---------------------------------------------------------------------------
// 8-phase GEMM (validated r9: 760 TF, MfmaUtil 32%). 256x256 tile, BK=64,
// 512 threads = 8 waves (2M x 4N). 4 phases per K-tile, counted vmcnt(8),
// setprio around MFMA, conflict-free chunk-XOR LDS (pre-swizzled source).
// EPI 6: B rows are 16-col-interleaved up1|up2 stacks; epilogue computes
// G[row][gcol] = bf16(gelu(acc_even + b1) * (acc_odd + b2)) register-locally.
// ---------------------------------------------------------------------------
template<int EPI>
__global__ __launch_bounds__(512)
void gemm8p(const uint16_t* __restrict__ A, const uint16_t* __restrict__ Bt,
            const float* __restrict__ bias0, const float* __restrict__ bias1,
            const float* __restrict__ auxF, const uint16_t* __restrict__ auxB,
            float* __restrict__ Cf, uint16_t* __restrict__ Cb0, uint16_t* __restrict__ Cb1,
            int M, int N, int K, int SPLIT)
{
  __shared__ alignas(16) char smem[131072];   // A: 2x32KB @0, B: 2x32KB @64KB
  const int tid = threadIdx.x, lane = tid & 63, wid = tid >> 6;
  const int wm = wid >> 2, wn = wid & 3;
  const int la = lane & 15, lq = lane >> 4;
  const int n0 = blockIdx.x * 256, m0 = blockIdx.y * 256;

  const int rt = tid >> 3;
  const int gs = (tid & 7) ^ (rt & 7);
  const uint16_t* srcA = A  + (size_t)(m0 + rt) * K + gs * 8;
  const uint16_t* srcB = Bt + (size_t)(n0 + rt) * K + gs * 8;

  const int rowAb = (wm * 128 + la) * 128;
  const int rowBb = (wn * 64 + la) * 128;
  const int ck0 = ((lq)     ^ (la & 7)) * 16;
  const int ck1 = ((4 + lq) ^ (la & 7)) * 16;

  f32x4 acc[8][4];
  const f32x4 fz = {0.f, 0.f, 0.f, 0.f};
#pragma unroll
  for (int m = 0; m < 8; ++m)
#pragma unroll
    for (int n = 0; n < 4; ++n) acc[m][n] = fz;

  bf16x8 aF[4][2], bF0[2][2], bF1[2][2];
  const int NT = K >> 6;

#define STAGE_A8(KT, BUF) do { _Pragma("unroll")                              \
    for (int l = 0; l < 4; ++l)                                               \
      __builtin_amdgcn_global_load_lds(                                       \
          (gas_ptr)(srcA + (size_t)(KT) * 64 + (size_t)l * 64 * K),           \
          (las_ptr)(smem + (BUF) * 32768 + (l * 512 + tid) * 16), 16, 0, 0);  \
  } while (0)
#define STAGE_B8(KT, BUF) do { _Pragma("unroll")                              \
    for (int l = 0; l < 4; ++l)                                               \
      __builtin_amdgcn_global_load_lds(                                       \
          (gas_ptr)(srcB + (size_t)(KT) * 64 + (size_t)l * 64 * K),           \
          (las_ptr)(smem + 65536 + (BUF) * 32768 + (l * 512 + tid) * 16),     \
          16, 0, 0);                                                          \
  } while (0)
#define RD_B8(DST, NH, BUF) do { _Pragma("unroll")                            \
    for (int nq = 0; nq < 2; ++nq) {                                          \
      int ro_ = 65536 + (BUF) * 32768 + rowBb + ((NH) * 2 + nq) * 2048;       \
      DST[nq][0] = *(const bf16x8*)(smem + ro_ + ck0);                        \
      DST[nq][1] = *(const bf16x8*)(smem + ro_ + ck1);                        \
    }                                                                         \
  } while (0)
#define RD_A8(MHS, BUF) do { _Pragma("unroll")                                \
    for (int mq = 0; mq < 4; ++mq) {                                          \
      int ro_ = (BUF) * 32768 + rowAb + ((MHS) * 4 + mq) * 2048;              \
      aF[mq][0] = *(const bf16x8*)(smem + ro_ + ck0);                         \
      aF[mq][1] = *(const bf16x8*)(smem + ro_ + ck1);                         \
    }                                                                         \
  } while (0)
#define MM8(MHS, NH, BF) do { _Pragma("unroll")                               \
    for (int mq = 0; mq < 4; ++mq)                                            \
      _Pragma("unroll")                                                       \
      for (int nq = 0; nq < 2; ++nq) {                                        \
        acc[(MHS)*4+mq][(NH)*2+nq] = __builtin_amdgcn_mfma_f32_16x16x32_bf16( \
            aF[mq][0], BF[nq][0], acc[(MHS)*4+mq][(NH)*2+nq], 0, 0, 0);       \
        acc[(MHS)*4+mq][(NH)*2+nq] = __builtin_amdgcn_mfma_f32_16x16x32_bf16( \
            aF[mq][1], BF[nq][1], acc[(MHS)*4+mq][(NH)*2+nq], 0, 0, 0);       \
      }                                                                       \
  } while (0)
#define BARR() __builtin_amdgcn_s_barrier()

  STAGE_A8(0, 0); STAGE_B8(0, 0);
  STAGE_A8(1, 1); STAGE_B8(1, 1);
  asm volatile("s_waitcnt vmcnt(8)" ::: "memory");
  BARR();

  for (int t = 0; t < NT; ++t) {
    const int buf = t & 1;
    const bool pf = (t + 2 < NT);
    RD_B8(bF0, 0, buf); RD_A8(0, buf);
    BARR();
    __builtin_amdgcn_s_setprio(1); MM8(0, 0, bF0); __builtin_amdgcn_s_setprio(0);
    BARR();
    RD_B8(bF1, 1, buf);
    BARR();
    __builtin_amdgcn_s_setprio(1); MM8(0, 1, bF1); __builtin_amdgcn_s_setprio(0);
    BARR();
    RD_A8(1, buf);
    if (pf) STAGE_B8(t + 2, buf);
    BARR();
    __builtin_amdgcn_s_setprio(1); MM8(1, 0, bF0); __builtin_amdgcn_s_setprio(0);
    BARR();
    if (pf) STAGE_A8(t + 2, buf);
    BARR();
    __builtin_amdgcn_s_setprio(1); MM8(1, 1, bF1); __builtin_amdgcn_s_setprio(0);
    asm volatile("s_waitcnt vmcnt(8)" ::: "memory");
    BARR();
  }
#undef STAGE_A8
#undef STAGE_B8
#undef RD_B8
#undef RD_A8
#undef MM8
#undef BARR

  if constexpr (EPI == 6) {
    // interleaved gated MLP: W-row w = n0+wn*64+n*16+la; half = n&1;
    // gcol = n0/2 + wn*32 + (n/2)*16 + la; G stride = N/2.
    const int GN = N >> 1;
#pragma unroll
    for (int np = 0; np < 2; ++np) {
      int gcol = (n0 >> 1) + wn * 32 + np * 16 + la;
      float b1 = bias0[gcol], b2 = bias1[gcol];
#pragma unroll
      for (int m = 0; m < 8; ++m) {
        int rbase = m0 + wm * 128 + m * 16 + lq * 4;
#pragma unroll
        for (int r = 0; r < 4; ++r) {
          int row = rbase + r;
          float v1 = acc[m][2*np][r] + b1;
          float v2 = acc[m][2*np+1][r] + b2;
          Cb0[(size_t)row * GN + gcol] = f32_to_bf16_rne(gelu_exact(v1) * v2);
        }
      }
    }
  } else {
#pragma unroll
    for (int n = 0; n < 4; ++n) {
      int col = n0 + wn * 64 + n * 16 + la;
      const bool second = (col >= SPLIT);
      float bv = second ? bias1[col - SPLIT] : bias0[col];
#pragma unroll
      for (int m = 0; m < 8; ++m) {
        int rbase = m0 + wm * 128 + m * 16 + lq * 4;
#pragma unroll
        for (int r = 0; r < 4; ++r) {
          int row = rbase + r;
          size_t idx = (size_t)row * N + col;
          epi_store<EPI>(acc[m][n][r] + bv, idx, row, col, N, SPLIT, auxF, auxB, Cf, Cb0, Cb1, second);
        }
      }
    }
  }
}

// ---------------------------------------------------------------------------
// 2-phase GEMM (validated r8 = m233 parity). BM x 256, BK=64, 8 waves.
// ---------------------------------------------------------------------------
template<int EPI, int BM>
__global__ __launch_bounds__(512)
void gemm2p(const uint16_t* __restrict__ A, const uint16_t* __restrict__ Bt,
            const float* __restrict__ bias0, const float* __restrict__ bias1,
            const float* __restrict__ auxF, const uint16_t* __restrict__ auxB,
            float* __restrict__ Cf, uint16_t* __restrict__ Cb0, uint16_t* __restrict__ Cb1,
            int M, int N, int K, int SPLIT)
{
  constexpr int BN = 256;
  constexpr int M_REP   = BM / 32;
  constexpr int LOADS_A = BM / 64;
  constexpr int LOADS_B = BN / 64;
  constexpr int ABYTES  = 2 * BM * 128;
  __shared__ alignas(16) char smem[2 * (BM + BN) * 128];

  const int tid  = threadIdx.x;
  const int lane = tid & 63;
  const int wid  = tid >> 6;
  const int wm = wid >> 2, wn = wid & 3;
  const int la = lane & 15, lq = lane >> 4;
  const int n0 = blockIdx.x * BN;
  const int m0 = blockIdx.y * BM;

  const int rt = tid >> 3;
  const int gs = (tid & 7) ^ (rt & 7);
  const uint16_t* srcA = A  + (size_t)(m0 + rt) * K + gs * 8;
  const uint16_t* srcB = Bt + (size_t)(n0 + rt) * K + gs * 8;

  const int rowAb = (wm * (BM / 2) + la) * 128;
  const int rowBb = (wn * 64 + la) * 128;
  const int ck0 = ((lq)     ^ (la & 7)) * 16;
  const int ck1 = ((4 + lq) ^ (la & 7)) * 16;

  f32x4 acc[M_REP][4];
  const f32x4 fz = {0.f, 0.f, 0.f, 0.f};
#pragma unroll
  for (int m = 0; m < M_REP; ++m)
#pragma unroll
    for (int n = 0; n < 4; ++n) acc[m][n] = fz;

  const int NT = K >> 6;

#define STAGE(KT, BUF) do {                                                   \
    const uint16_t* sa_ = srcA + (size_t)(KT) * 64;                           \
    const uint16_t* sb_ = srcB + (size_t)(KT) * 64;                           \
    _Pragma("unroll")                                                         \
    for (int l = 0; l < LOADS_A; ++l)                                         \
      __builtin_amdgcn_global_load_lds((gas_ptr)(sa_ + (size_t)l * 64 * K),   \
          (las_ptr)(smem + (BUF) * BM * 128 + (l * 512 + tid) * 16), 16, 0, 0);\
    _Pragma("unroll")                                                         \
    for (int l = 0; l < LOADS_B; ++l)                                         \
      __builtin_amdgcn_global_load_lds((gas_ptr)(sb_ + (size_t)l * 64 * K),   \
          (las_ptr)(smem + ABYTES + (BUF) * BN * 128 + (l * 512 + tid) * 16), \
          16, 0, 0);                                                          \
  } while (0)

  STAGE(0, 0);
  asm volatile("s_waitcnt vmcnt(0)" ::: "memory");
  __builtin_amdgcn_s_barrier();

  int cur = 0;
  for (int kt = 0; kt < NT; ++kt) {
    const bool pf = (kt + 1 < NT);
    if (pf) STAGE(kt + 1, cur ^ 1);

    const int offA = cur * BM * 128;
    const int offB = ABYTES + cur * BN * 128;

    bf16x8 bF[4][2];
#pragma unroll
    for (int n = 0; n < 4; ++n) {
      int ro = offB + rowBb + n * 2048;
      bF[n][0] = *(const bf16x8*)(smem + ro + ck0);
      bF[n][1] = *(const bf16x8*)(smem + ro + ck1);
    }
    __builtin_amdgcn_s_setprio(1);
#pragma unroll
    for (int m = 0; m < M_REP; ++m) {
      int ro = offA + rowAb + m * 2048;
      bf16x8 a0 = *(const bf16x8*)(smem + ro + ck0);
      bf16x8 a1 = *(const bf16x8*)(smem + ro + ck1);
#pragma unroll
      for (int n = 0; n < 4; ++n) {
        acc[m][n] = __builtin_amdgcn_mfma_f32_16x16x32_bf16(a0, bF[n][0], acc[m][n], 0, 0, 0);
        acc[m][n] = __builtin_amdgcn_mfma_f32_16x16x32_bf16(a1, bF[n][1], acc[m][n], 0, 0, 0);
      }
    }
    __builtin_amdgcn_s_setprio(0);

    if (pf) {
      asm volatile("s_waitcnt vmcnt(0)" ::: "memory");
      __builtin_amdgcn_s_barrier();
      cur ^= 1;
    }
  }
#undef STAGE

#pragma unroll
  for (int n = 0; n < 4; ++n) {
    int col = n0 + wn * 64 + n * 16 + la;
    const bool second = (col >= SPLIT);
    float bv = second ? bias1[col - SPLIT] : bias0[col];
#pragma unroll
    for (int m = 0; m < M_REP; ++m) {
      int rbase = m0 + wm * (BM / 2) + m * 16 + lq * 4;
#pragma unroll
      for (int r = 0; r < 4; ++r) {
        int row = rbase + r;
        size_t idx = (size_t)row * N + col;
        epi_store<EPI>(acc[m][n][r] + bv, idx, row, col, N, SPLIT, auxF, auxB, Cf, Cb0, Cb1, second);
      }
    }
  }
}

// ---------------------------------------------------------------------------
// Convert + transpose: in[R][C] f32 -> out[C][R] bf16. 64x64 tiles.
// ---------------------------------------------------------------------------
__global__ __launch_bounds__(256)
void cvt_transpose(const float* __restrict__ in, uint16_t* __restrict__ out, int R, int C)
{
  __shared__ float tile[64][65];
  const int r0 = blockIdx.y * 64, c0 = blockIdx.x * 64;
  const int t = threadIdx.x;
  const int lc = (t & 15) * 4;
  const int lr0 = t >> 4;
#pragma unroll
  for (int j = 0; j < 4; j++){
    int lr = lr0 + j*16;
    float4 v = *(const float4*)(in + (size_t)(r0 + lr) * C + c0 + lc);
    tile[lr][lc+0] = v.x; tile[lr][lc+1] = v.y; tile[lr][lc+2] = v.z; tile[lr][lc+3] = v.w;
  }
  __syncthreads();
  const int oc = t >> 2;
  const int rseg = (t & 3) * 16;
  alignas(16) uint16_t tmp[16];
#pragma unroll
  for (int j = 0; j < 16; j++) tmp[j] = f32_to_bf16_rne(tile[rseg + j][oc]);
  uint4* dst = (uint4*)(out + (size_t)(c0 + oc) * R + r0 + rseg);
  dst[0] = *(const uint4*)(&tmp[0]);
  dst[1] = *(const uint4*)(&tmp[8]);
}

// ---------------------------------------------------------------------------
// Convert + transpose with 16-col interleave for gated-MLP fusion:
// source col c -> output W-row (c>>4)*32 + half*16 + (c&15).
// ---------------------------------------------------------------------------
__global__ __launch_bounds__(256)
void cvt_transpose_ileave(const float* __restrict__ in, uint16_t* __restrict__ out,
                          int R, int C, int half)
{
  __shared__ float tile[64][65];
  const int r0 = blockIdx.y * 64, c0 = blockIdx.x * 64;
  const int t = threadIdx.x;
  const int lc = (t & 15) * 4;
  const int lr0 = t >> 4;
#pragma unroll
  for (int j = 0; j < 4; j++){
    int lr = lr0 + j*16;
    float4 v = *(const float4*)(in + (size_t)(r0 + lr) * C + c0 + lc);
    tile[lr][lc+0] = v.x; tile[lr][lc+1] = v.y; tile[lr][lc+2] = v.z; tile[lr][lc+3] = v.w;
  }
  __syncthreads();
  const int oc = t >> 2;
  const int rseg = (t & 3) * 16;
  const int c = c0 + oc;
  const int wrow = ((c >> 4) << 5) + half * 16 + (c & 15);
  alignas(16) uint16_t tmp[16];
#pragma unroll
  for (int j = 0; j < 16; j++) tmp[j] = f32_to_bf16_rne(tile[rseg + j][oc]);
  uint4* dst = (uint4*)(out + (size_t)wrow * R + r0 + rseg);
  dst[0] = *(const uint4*)(&tmp[0]);
  dst[1] = *(const uint4*)(&tmp[8]);
}

// ---------------------------------------------------------------------------
// RMSNorm f32-in: per row of D -> bf16.
// ---------------------------------------------------------------------------
__global__ __launch_bounds__(256)
void rmsnorm_kernel(const float* __restrict__ x, const float* __restrict__ w,
                    uint16_t* __restrict__ out, int D)
{
  const int row = blockIdx.x;
  const float* xr = x + (size_t)row * D;
  const int base = threadIdx.x * 8;
  float4 va = *(const float4*)(xr + base);
  float4 vb = *(const float4*)(xr + base + 4);
  float ss = va.x*va.x + va.y*va.y + va.z*va.z + va.w*va.w
           + vb.x*vb.x + vb.y*vb.y + vb.z*vb.z + vb.w*vb.w;
#pragma unroll
  for (int o = 32; o > 0; o >>= 1) ss += __shfl_xor(ss, o);
  __shared__ float red[4];
  if ((threadIdx.x & 63) == 0) red[threadIdx.x >> 6] = ss;
  __syncthreads();
  float tot = red[0] + red[1] + red[2] + red[3];
  float inv = rsqrtf(tot / (float)D + 1e-8f);
  float4 wa = *(const float4*)(w + base);
  float4 wb = *(const float4*)(w + base + 4);
  alignas(16) uint16_t tmp[8];
  tmp[0] = f32_to_bf16_rne(va.x * wa.x * inv);
  tmp[1] = f32_to_bf16_rne(va.y * wa.y * inv);
  tmp[2] = f32_to_bf16_rne(va.z * wa.z * inv);
  tmp[3] = f32_to_bf16_rne(va.w * wa.w * inv);
  tmp[4] = f32_to_bf16_rne(vb.x * wb.x * inv);
  tmp[5] = f32_to_bf16_rne(vb.y * wb.y * inv);
  tmp[6] = f32_to_bf16_rne(vb.z * wb.z * inv);
  tmp[7] = f32_to_bf16_rne(vb.w * wb.w * inv);
  *(uint4*)(out + (size_t)row * D + base) = *(const uint4*)tmp;
}

// ---------------------------------------------------------------------------
// RMSNorm bf16-in: per row of D -> bf16.
// ---------------------------------------------------------------------------
__global__ __launch_bounds__(256)
void rmsnorm_bf16_kernel(const uint16_t* __restrict__ x, const float* __restrict__ w,
                         uint16_t* __restrict__ out, int D)
{
  const int row = blockIdx.x;
  const uint16_t* xr = x + (size_t)row * D;
  const int base = threadIdx.x * 8;
  uint4 v = *(const uint4*)(xr + base);
  const uint16_t* vp = (const uint16_t*)&v;
  float xs[8];
  float ss = 0.f;
#pragma unroll
  for (int j = 0; j < 8; ++j){ xs[j] = bf16_to_f32(vp[j]); ss += xs[j]*xs[j]; }
#pragma unroll
  for (int o = 32; o > 0; o >>= 1) ss += __shfl_xor(ss, o);
  __shared__ float red[4];
  if ((threadIdx.x & 63) == 0) red[threadIdx.x >> 6] = ss;
  __syncthreads();
  float tot = red[0] + red[1] + red[2] + red[3];
  float inv = rsqrtf(tot / (float)D + 1e-8f);
  float4 wa = *(const float4*)(w + base);
  float4 wb = *(const float4*)(w + base + 4);
  float wv[8] = {wa.x, wa.y, wa.z, wa.w, wb.x, wb.y, wb.z, wb.w};
  alignas(16) uint16_t tmp[8];
#pragma unroll
  for (int j = 0; j < 8; ++j) tmp[j] = f32_to_bf16_rne(xs[j] * wv[j] * inv);
  *(uint4*)(out + (size_t)row * D + base) = *(const uint4*)tmp;
}

// ---------------------------------------------------------------------------
// Depthwise causal conv K=4 along t, bf16 in/out. grid (H/256, S/128, B)
// ---------------------------------------------------------------------------
__global__ __launch_bounds__(256)
void conv_kernel(const uint16_t* __restrict__ xin, const float* __restrict__ cw,
                 const float* __restrict__ cb, uint16_t* __restrict__ yout,
                 int S, int H)
{
  const int h = blockIdx.x * 256 + threadIdx.x;
  const int b = blockIdx.z;
  const int t0 = blockIdx.y * 128;
  const float w0 = cw[h], w1 = cw[H + h], w2 = cw[2*H + h], w3 = cw[3*H + h];
  const float bias = cb[h];
  const size_t colbase = (size_t)b * S * H + h;
  float xm3 = (t0 >= 3) ? bf16_to_f32(xin[colbase + (size_t)(t0-3)*H]) : 0.f;
  float xm2 = (t0 >= 2) ? bf16_to_f32(xin[colbase + (size_t)(t0-2)*H]) : 0.f;
  float xm1 = (t0 >= 1) ? bf16_to_f32(xin[colbase + (size_t)(t0-1)*H]) : 0.f;
  for (int t = t0; t < t0 + 128; ++t){
    size_t idx = colbase + (size_t)t * H;
    float xt = bf16_to_f32(xin[idx]);
    float y = w0*xm3 + w1*xm2 + w2*xm1 + w3*xt + bias;
    yout[idx] = f32_to_bf16_rne(y);
    xm3 = xm2; xm2 = xm1; xm1 = xt;
  }
}

// ---------------------------------------------------------------------------
// RG-LRU chunked scan over bf16 inputs.
// ---------------------------------------------------------------------------
__device__ __forceinline__ void rglru_ab(float rp, float ip, float xc, float coef,
                                         float& a, float& bb)
{
  float r  = 1.f / (1.f + expf(-rp));
  float la = coef * r;
  a = expf(la);
  float mult = sqrtf(-expm1f(2.f * la));
  float ig = 1.f / (1.f + expf(-ip));
  bb = mult * ig * xc;
}

__global__ __launch_bounds__(256)
void scan_phase1(const uint16_t* __restrict__ gpre, const uint16_t* __restrict__ convb,
                 const float* __restrict__ ap,
                 float* __restrict__ SA, float* __restrict__ SB,
                 int S, int H, int T0, int NC)
{
  const int h = blockIdx.x * 256 + threadIdx.x;
  const int j = blockIdx.y, b = blockIdx.z;
  const float coef = -8.f * log1pf(expf(ap[h]));
  size_t rowb = (size_t)b * S + (size_t)j * T0;
  float A = 1.f, Bc = 0.f;
  for (int t = 0; t < T0; ++t){
    size_t row = rowb + t;
    float rp = bf16_to_f32(gpre[row * 2 * H + h]);
    float ip = bf16_to_f32(gpre[row * 2 * H + H + h]);
    float xc = bf16_to_f32(convb[row * H + h]);
    float a, bb; rglru_ab(rp, ip, xc, coef, a, bb);
    A *= a; Bc = a * Bc + bb;
  }
  size_t o = ((size_t)b * NC + j) * H + h;
  SA[o] = A; SB[o] = Bc;
}

__global__ __launch_bounds__(256)
void scan_phase2(const float* __restrict__ SA, const float* __restrict__ SB,
                 float* __restrict__ SH, int H, int NC)
{
  const int h = blockIdx.x * 256 + threadIdx.x;
  const int b = blockIdx.y;
  float hh = 0.f;
  for (int j = 0; j < NC; ++j){
    size_t o = ((size_t)b * NC + j) * H + h;
    SH[o] = hh;
    hh = SA[o] * hh + SB[o];
  }
}

__global__ __launch_bounds__(256)
void scan_phase3(const uint16_t* __restrict__ gpre, const uint16_t* __restrict__ convb,
                 const float* __restrict__ ap, const float* __restrict__ SH,
                 const uint16_t* __restrict__ left, uint16_t* __restrict__ lr,
                 int S, int H, int T0, int NC)
{
  const int h = blockIdx.x * 256 + threadIdx.x;
  const int j = blockIdx.y, b = blockIdx.z;
  const float coef = -8.f * log1pf(expf(ap[h]));
  float hh = SH[((size_t)b * NC + j) * H + h];
  size_t rowb = (size_t)b * S + (size_t)j * T0;
  for (int t = 0; t < T0; ++t){
    size_t row = rowb + t;
    float rp = bf16_to_f32(gpre[row * 2 * H + h]);
    float ip = bf16_to_f32(gpre[row * 2 * H + H + h]);
    float xc = bf16_to_f32(convb[row * H + h]);
    float a, bb; rglru_ab(rp, ip, xc, coef, a, bb);
    hh = a * hh + bb;
    lr[row * H + h] = f32_to_bf16_rne(bf16_to_f32(left[row * H + h]) * hh);
  }
}

// ---------------------------------------------------------------------------
extern "C" void kernel_launch(void* const* d_in, const int* in_sizes, int n_in,
                              void* d_out, int out_size, void* d_ws, size_t ws_size,
                              hipStream_t stream)
{
  const int B = 2, S = 2048, D = 2048, H = 2048, F = 6144;
  const int M = B * S;            // 4096
  const int NC = 32, T0 = S / NC; // scan chunking

  const float* x       = (const float*)d_in[0];
  const float* norm1_w = (const float*)d_in[1];
  const float* left_W  = (const float*)d_in[2];
  const float* left_b  = (const float*)d_in[3];
  const float* right_W = (const float*)d_in[4];
  const float* right_b = (const float*)d_in[5];
  const float* conv_w  = (const float*)d_in[6];
  const float* conv_b  = (const float*)d_in[7];
  const float* ga_W    = (const float*)d_in[8];
  const float* ga_b    = (const float*)d_in[9];
  const float* gx_W    = (const float*)d_in[10];
  const float* gx_b    = (const float*)d_in[11];
  const float* a_param = (const float*)d_in[12];
  const float* out_W   = (const float*)d_in[13];
  const float* out_b   = (const float*)d_in[14];
  const float* norm2_w = (const float*)d_in[15];
  const float* up1_W   = (const float*)d_in[16];
  const float* up1_b   = (const float*)d_in[17];
  const float* up2_W   = (const float*)d_in[18];
  const float* up2_b   = (const float*)d_in[19];
  const float* down_W  = (const float*)d_in[20];
  const float* down_b  = (const float*)d_in[21];

  char* ws = (char*)d_ws;
  size_t off = 0;
  auto alloc = [&](size_t bytes) -> char* {
    char* p = ws + off; off += (bytes + 255) & ~(size_t)255; return p;
  };
  // Overlay: G/T1 [M][F] bf16 (50.33 MB) === XN + LEFT + RPRE (3 x 16.78 MB),
  // all dead by step 8 (XN after step 2, RPRE after step 3, LEFT after step 5).
  uint16_t* WT    = (uint16_t*)alloc((size_t)2 * F * D * 2); // weights bf16^T (interleaved up pair)
  uint16_t* XN    = (uint16_t*)alloc((size_t)M * D * 2);
  uint16_t* LEFT  = (uint16_t*)alloc((size_t)M * H * 2);
  uint16_t* RPRE  = (uint16_t*)alloc((size_t)M * H * 2);
  uint16_t* CONVB = (uint16_t*)alloc((size_t)M * H * 2);
  uint16_t* GPRE  = (uint16_t*)alloc((size_t)M * 2 * H * 2);
  uint16_t* LR    = (uint16_t*)alloc((size_t)M * H * 2);
  uint16_t* X1B   = (uint16_t*)alloc((size_t)M * D * 2);   // residual x1 (bf16)
  uint16_t* X1N   = (uint16_t*)alloc((size_t)M * D * 2);
  float*    SA    = (float*)   alloc((size_t)B * NC * H * 4);
  float*    SB    = (float*)   alloc((size_t)B * NC * H * 4);
  float*    SHB   = (float*)   alloc((size_t)B * NC * H * 4);
  uint16_t* G     = XN;    // overlay [M][F], live steps 8-9

  if (off > ws_size) {
    fprintf(stderr, "kernel_launch: ws too small, need %zu have %zu\n", off, ws_size);
    return;
  }

  float* OUT = (float*)d_out;
  dim3 blk(256);
  dim3 gblk(512);

  // 1. xn = rmsnorm(x)
  rmsnorm_kernel<<<M, blk, 0, stream>>>(x, norm1_w, XN, D);

  // 2. merged left|right GEMM (8-phase): N=4096, SPLIT=2048 (gelu | raw)
  cvt_transpose<<<dim3(H/64, D/64), blk, 0, stream>>>(left_W, WT, D, H);
  cvt_transpose<<<dim3(H/64, D/64), blk, 0, stream>>>(right_W, WT + (size_t)H * D, D, H);
  gemm8p<1><<<dim3((2*H)/256, M/256), gblk, 0, stream>>>(
      XN, WT, left_b, right_b, nullptr, nullptr, nullptr, LEFT, RPRE, M, 2*H, D, H);

  // 3. conv (causal depthwise) bf16 -> bf16
  conv_kernel<<<dim3(H/256, S/128, B), blk, 0, stream>>>(RPRE, conv_w, conv_b, CONVB, S, H);

  // 4. merged gate GEMM (8-phase): GPRE[M][2H]
  cvt_transpose<<<dim3(H/64, H/64), blk, 0, stream>>>(ga_W, WT, H, H);
  cvt_transpose<<<dim3(H/64, H/64), blk, 0, stream>>>(gx_W, WT + (size_t)H * H, H, H);
  gemm8p<2><<<dim3((2*H)/256, M/256), gblk, 0, stream>>>(
      CONVB, WT, ga_b, gx_b, nullptr, nullptr, nullptr, GPRE, nullptr, M, 2*H, H, H);

  // 5. rg-lru chunked scan; phase3 fuses lr = bf16(left * h)
  scan_phase1<<<dim3(H/256, NC, B), blk, 0, stream>>>(GPRE, CONVB, a_param, SA, SB, S, H, T0, NC);
  scan_phase2<<<dim3(H/256, B), blk, 0, stream>>>(SA, SB, SHB, H, NC);
  scan_phase3<<<dim3(H/256, NC, B), blk, 0, stream>>>(GPRE, CONVB, a_param, SHB, LEFT, LR, S, H, T0, NC);

  // 6. x1 = bf16(lr @ out_W + out_b + x)   (EPI4, bf16 residual out)
  cvt_transpose<<<dim3(D/64, H/64), blk, 0, stream>>>(out_W, WT, H, D);
  gemm2p<4, 128><<<dim3(D/256, M/128), gblk, 0, stream>>>(
      LR, WT, out_b, out_b, x, nullptr, nullptr, X1B, nullptr, M, D, H, D);

  // 7. x1n = rmsnorm(x1)  (bf16 in)
  rmsnorm_bf16_kernel<<<M, blk, 0, stream>>>(X1B, norm2_w, X1N, D);

  // 8. fused gated-up GEMM (8-phase, EPI6): N=12288 interleaved up1|up2;
  //    epilogue writes G = bf16(gelu(up1) * up2) directly (no mul pass).
  cvt_transpose_ileave<<<dim3(F/64, D/64), blk, 0, stream>>>(up1_W, WT, D, F, 0);
  cvt_transpose_ileave<<<dim3(F/64, D/64), blk, 0, stream>>>(up2_W, WT, D, F, 1);
  gemm8p<6><<<dim3((2*F)/256, M/256), gblk, 0, stream>>>(
      X1N, WT, up1_b, up2_b, nullptr, nullptr, nullptr, G, nullptr, M, 2*F, D, 2*F);

  // 9. out = g @ down_W + down_b + x1  (EPI5: f32 out, bf16 residual)
  cvt_transpose<<<dim3(D/64, F/64), blk, 0, stream>>>(down_W, WT, F, D);
  gemm2p<5, 128><<<dim3(D/256, M/128), gblk, 0, stream>>>(
      G, WT, down_b, down_b, nullptr, X1B, OUT, nullptr, nullptr, M, D, F, D);
}